// Round 14
// baseline (3842.222 us; speedup 1.0000x reference)
//
#include <hip/hip_runtime.h>
#include <math.h>

static constexpr int C_IN    = 32;
static constexpr int T_STEPS = 12;
static constexpr int D_HID   = 128;
static constexpr int KTOT    = 3*C_IN + 3*D_HID;  // 480
static constexpr int GDIM    = 4*D_HID;           // 512
static constexpr int XW      = T_STEPS*C_IN;      // 384: x-plane row width
static constexpr int HW      = 3*D_HID;           // 384: h-basis row width

static inline int cdiv(long a, int b) { return (int)((a + b - 1) / b); }

typedef __attribute__((ext_vector_type(8))) short bf16x8;
typedef __attribute__((ext_vector_type(4))) float f32x4;

__device__ __forceinline__ float bf2f(unsigned int u16) {
  union { unsigned int u; float f; } v; v.u = u16 << 16; return v.f;
}
__device__ __forceinline__ unsigned short f2bf(float f) {
  union { float f; unsigned int u; } v; v.f = f;
  unsigned int u = v.u + 0x7fffu + ((v.u >> 16) & 1u);  // RNE
  return (unsigned short)(u >> 16);
}
__device__ __forceinline__ void split2(float a, unsigned short& h, unsigned short& l) {
  h = f2bf(a);
  l = f2bf(a - bf2f(h));
}
__device__ __forceinline__ float fsig(float x) { return 1.0f/(1.0f + __expf(-x)); }
__device__ __forceinline__ float ftanh(float x) {
  float e = __expf(2.0f*x);
  return 1.0f - 2.0f/(e + 1.0f);
}

// ---------------- CSR build ----------------

__global__ void k_zero_i(int* __restrict__ p, int n) {
  int i = blockIdx.x*blockDim.x + threadIdx.x;
  if (i < n) p[i] = 0;
}

__global__ void k_count(const int* __restrict__ src, const int* __restrict__ dst,
                        int* __restrict__ cnt, int* __restrict__ deg, int E) {
  int e = blockIdx.x*blockDim.x + threadIdx.x;
  if (e < E) {
    atomicAdd(&cnt[dst[e]], 1);
    atomicAdd(&deg[src[e]], 1);
  }
}

__global__ void k_dis(const int* __restrict__ deg, float* __restrict__ dis, int n) {
  int i = blockIdx.x*blockDim.x + threadIdx.x;
  if (i < n) {
    int d = deg[i];
    dis[i] = d > 0 ? rsqrtf((float)d) : 0.0f;
  }
}

__global__ __launch_bounds__(1024) void k_scan(const int* __restrict__ cnt,
                                               int* __restrict__ rowptr, int n) {
  __shared__ int wsum[16];
  __shared__ int carry_s;
  int tid = threadIdx.x; int lane = tid & 63; int wv_ = tid >> 6;
  if (tid == 0) { carry_s = 0; rowptr[0] = 0; }
  __syncthreads();
  for (int base = 0; base < n; base += 1024) {
    int i = base + tid;
    int s = (i < n) ? cnt[i] : 0;
    #pragma unroll
    for (int off = 1; off < 64; off <<= 1) {
      int t = __shfl_up(s, off);
      if (lane >= off) s += t;
    }
    if (lane == 63) wsum[wv_] = s;
    __syncthreads();
    if (tid < 16) {
      int ws = wsum[tid];
      #pragma unroll
      for (int off = 1; off < 16; off <<= 1) {
        int t = __shfl_up(ws, off);
        if (tid >= off) ws += t;
      }
      wsum[tid] = ws;
    }
    __syncthreads();
    int offw = carry_s + (wv_ > 0 ? wsum[wv_-1] : 0);
    if (i < n) rowptr[i+1] = offw + s;
    __syncthreads();
    if (tid == 0) carry_s = carry_s + wsum[15];
    __syncthreads();
  }
}

__global__ void k_fill(const int* __restrict__ src, const int* __restrict__ dst,
                       const int* __restrict__ rowptr, int* __restrict__ fil,
                       const float* __restrict__ dis,
                       int* __restrict__ colI, float* __restrict__ wvv, int E) {
  int e = blockIdx.x*blockDim.x + threadIdx.x;
  if (e < E) {
    int d = dst[e], s = src[e];
    int p = rowptr[d] + atomicAdd(&fil[d], 1);
    colI[p] = s;
    wvv[p] = -dis[s] * dis[d];
  }
}

// ---------------- weight packing ----------------
// Column permutation p = 4*d + g (gate-interleaved). Chebyshev refold:
// basis [v, y1=Lv, y2=L(Lv)] with weights [W0-W2, W1, 2*W2].
// k8-interleave: element (kk,p) at ((kt*4+kg)*512+p)*8+i, kk=kt*32+kg*8+i.

__global__ void k_packB(const float* __restrict__ Wx, const float* __restrict__ Wh,
                        unsigned short* __restrict__ BH, unsigned short* __restrict__ BL) {
  int idx = blockIdx.x*blockDim.x + threadIdx.x;
  if (idx >= KTOT*GDIM) return;
  int kk = idx / GDIM, p = idx % GDIM;
  int g = p & 3, d = p >> 2;
  float v;
  if (kk < 96) {
    int k3 = kk >> 5, c = kk & 31;
    auto wx = [&](int k) { return Wx[((((size_t)g*3 + k)*32 + c) << 7) + d]; };
    v = (k3 == 0) ? wx(0) - wx(2) : (k3 == 1) ? wx(1) : 2.0f*wx(2);
  } else {
    int kk2 = kk - 96;
    int k3 = kk2 >> 7, j = kk2 & 127;
    auto wh = [&](int k) { return Wh[((((size_t)g*3 + k)*128 + j) << 7) + d]; };
    v = (k3 == 0) ? wh(0) - wh(2) : (k3 == 1) ? wh(1) : 2.0f*wh(2);
  }
  unsigned short h, l; split2(v, h, l);
  int kt = kk >> 5, kg = (kk >> 3) & 3, i = kk & 7;
  size_t o = ((size_t)((kt*4 + kg)*GDIM + p))*8 + i;
  BH[o] = h; BL[o] = l;
}

__global__ void k_bias(const float* __restrict__ bx, const float* __restrict__ bh,
                       const float* __restrict__ bg, float* __restrict__ bsum) {
  int i = blockIdx.x*blockDim.x + threadIdx.x;
  if (i < GDIM) bsum[i] = bx[i] + bh[i] + bg[i];
}

// ---------------- staging ----------------

// P0[n][t*32+c] = bf16(x[n][c][t])  for all t at once
__global__ void k_xt_all(const float* __restrict__ x, unsigned short* __restrict__ P0,
                         long total) {
  long i = (long)blockIdx.x*blockDim.x + threadIdx.x;   // ((n*12+t)*32+c)
  if (i >= total) return;
  int c = (int)(i & 31);
  long nt = i >> 5;
  int t = (int)(nt % T_STEPS);
  long n = nt / T_STEPS;
  float v = x[(n*C_IN + c)*T_STEPS + t];
  P0[n*XW + t*C_IN + c] = f2bf(v);
}

// DST[n][0:384) = L_hat @ SRC   (compact planes, 96 uint2-lanes per node)
__global__ void k_spmm_x(const int* __restrict__ rowptr, const int* __restrict__ colI,
                         const float* __restrict__ wvv,
                         const unsigned short* __restrict__ SRC,
                         unsigned short* __restrict__ DST, int n) {
  int gt = blockIdx.x*blockDim.x + threadIdx.x;
  int node = gt / 96;
  int lane = gt - node*96;
  if (node >= n) return;
  const uint2* gp = (const uint2*)SRC;
  float a0 = 0.f, a1 = 0.f, a2 = 0.f, a3 = 0.f;
  int r0 = rowptr[node], r1 = rowptr[node+1];
  int e = r0;
  for (; e + 4 <= r1; e += 4) {
    int s0 = colI[e], s1 = colI[e+1], s2 = colI[e+2], s3 = colI[e+3];
    float w0 = wvv[e], w1 = wvv[e+1], w2 = wvv[e+2], w3 = wvv[e+3];
    uint2 u0 = gp[(size_t)s0*96 + lane];
    uint2 u1 = gp[(size_t)s1*96 + lane];
    uint2 u2 = gp[(size_t)s2*96 + lane];
    uint2 u3 = gp[(size_t)s3*96 + lane];
    a0 += w0*bf2f(u0.x & 0xffffu) + w1*bf2f(u1.x & 0xffffu)
        + w2*bf2f(u2.x & 0xffffu) + w3*bf2f(u3.x & 0xffffu);
    a1 += w0*bf2f(u0.x >> 16)     + w1*bf2f(u1.x >> 16)
        + w2*bf2f(u2.x >> 16)     + w3*bf2f(u3.x >> 16);
    a2 += w0*bf2f(u0.y & 0xffffu) + w1*bf2f(u1.y & 0xffffu)
        + w2*bf2f(u2.y & 0xffffu) + w3*bf2f(u3.y & 0xffffu);
    a3 += w0*bf2f(u0.y >> 16)     + w1*bf2f(u1.y >> 16)
        + w2*bf2f(u2.y >> 16)     + w3*bf2f(u3.y >> 16);
  }
  for (; e < r1; ++e) {
    int s = colI[e]; float w = wvv[e];
    uint2 u = gp[(size_t)s*96 + lane];
    a0 += w*bf2f(u.x & 0xffffu);
    a1 += w*bf2f(u.x >> 16);
    a2 += w*bf2f(u.y & 0xffffu);
    a3 += w*bf2f(u.y >> 16);
  }
  uint2 hw;
  hw.x = (unsigned int)f2bf(a0) | ((unsigned int)f2bf(a1) << 16);
  hw.y = (unsigned int)f2bf(a2) | ((unsigned int)f2bf(a3) << 16);
  ((uint2*)DST)[(size_t)node*96 + lane] = hw;
}

// h-side: y = L_hat @ GSRC (compact [n][128] bf16 = 256 B rows).
// COLUMN-CHUNKED for L2 locality: blockIdx.x = 64-B chunk (0..3). With
// gridDim.x=4, chunk c's blocks land on XCDs {c, c+4} (hardware round-robin
// on linear block id), so each XCD's gather working set is one chunk slice
// of the plane = 3.2 MB < 4 MB L2 -> gathers hit L2 (~34 TB/s) instead of
// L3 (~6 TB/s). Per node: 16 lanes = 4 slices x 4 edge-phases (divergence
// stays 4 nodes/wave; phases give implicit unroll-4); partial sums combined
// with 2 shfl_xor. Instruction count identical to the flat version.
__global__ void k_spmm_h(const int* __restrict__ rowptr, const int* __restrict__ colI,
                         const float* __restrict__ wvv,
                         const unsigned short* __restrict__ GSRC,
                         unsigned short* __restrict__ HB,
                         unsigned short* __restrict__ GOUT, int colO, int selfCol, int n) {
  const int chunk = blockIdx.x;              // 64-B chunk of the 256-B row
  const int t16 = threadIdx.x & 15;
  const int slice = t16 & 3;                 // 16-B slice within chunk
  const int ephase = t16 >> 2;               // edge phase 0..3
  const int node = blockIdx.y*16 + (threadIdx.x >> 4);
  if (node >= n) return;
  const unsigned sub = ((unsigned)chunk << 6) + ((unsigned)slice << 4);
  const char* gb = (const char*)GSRC + sub;
  float a0=0.f,a1=0.f,a2=0.f,a3=0.f,a4=0.f,a5=0.f,a6=0.f,a7=0.f;
  int r0 = rowptr[node], r1 = rowptr[node+1];
  for (int e = r0 + ephase; e < r1; e += 4) {
    unsigned off = (unsigned)colI[e] << 8;
    float w = wvv[e];
    uint4 u = *(const uint4*)(gb + off);
    a0 += w*bf2f(u.x & 0xffffu);
    a1 += w*bf2f(u.x >> 16);
    a2 += w*bf2f(u.y & 0xffffu);
    a3 += w*bf2f(u.y >> 16);
    a4 += w*bf2f(u.z & 0xffffu);
    a5 += w*bf2f(u.z >> 16);
    a6 += w*bf2f(u.w & 0xffffu);
    a7 += w*bf2f(u.w >> 16);
  }
  // combine the 4 edge-phases (lanes differing in bits 2,3 of t16)
  a0 += __shfl_xor(a0, 4); a1 += __shfl_xor(a1, 4);
  a2 += __shfl_xor(a2, 4); a3 += __shfl_xor(a3, 4);
  a4 += __shfl_xor(a4, 4); a5 += __shfl_xor(a5, 4);
  a6 += __shfl_xor(a6, 4); a7 += __shfl_xor(a7, 4);
  a0 += __shfl_xor(a0, 8); a1 += __shfl_xor(a1, 8);
  a2 += __shfl_xor(a2, 8); a3 += __shfl_xor(a3, 8);
  a4 += __shfl_xor(a4, 8); a5 += __shfl_xor(a5, 8);
  a6 += __shfl_xor(a6, 8); a7 += __shfl_xor(a7, 8);
  if (ephase == 0) {
    uint4 hw;
    hw.x = (unsigned int)f2bf(a0) | ((unsigned int)f2bf(a1) << 16);
    hw.y = (unsigned int)f2bf(a2) | ((unsigned int)f2bf(a3) << 16);
    hw.z = (unsigned int)f2bf(a4) | ((unsigned int)f2bf(a5) << 16);
    hw.w = (unsigned int)f2bf(a6) | ((unsigned int)f2bf(a7) << 16);
    *(uint4*)((char*)(HB + (size_t)node*HW + colO) + sub) = hw;
    if (GOUT) *(uint4*)((char*)(GOUT + (size_t)node*D_HID) + sub) = hw;
    if (selfCol >= 0) {
      uint4 own = *(const uint4*)(gb + ((unsigned)node << 8));
      *(uint4*)((char*)(HB + (size_t)node*HW + selfCol) + sub) = own;
    }
  }
}

// ---------------- fused MFMA GEMM + LSTM cell (r11 structure, unchanged) ----
// 128 rows x 128 packed cols, 4 waves, ~27 KB LDS (5 blocks/CU).
// bf16x2 (A bf16, B hi/lo). Single-buffer staging — both source-level
// pipelining attempts (r10 dbuf, r12 reg-prefetch) regressed; the 2-barrier
// staging loop is the measured-best structure at this size.
// Bank-conflict-free: A rows 42 shorts (21 dwords), B planes 1026 (513 dw).
// A k-tiles: kt 0,1,2 from P0/P1/P2 (+t*32), kt 3..14 from HB ((kt-3)*32).
// XCD-chunked bijective swizzle. Epilogue writes h ONLY to HG (race-free).

__global__ __launch_bounds__(256) void k_gemm_lstm(
    const unsigned short* __restrict__ P0, const unsigned short* __restrict__ P1,
    const unsigned short* __restrict__ P2, const unsigned short* __restrict__ HB,
    const unsigned short* __restrict__ BH, const unsigned short* __restrict__ BL,
    const float* __restrict__ bsum, const float* __restrict__ wcp,
    float* __restrict__ Cst, float* __restrict__ Ht,
    unsigned short* __restrict__ HG,
    int N, int first, int ntk, int t) {
  union SMem {
    struct { unsigned short As[128][42]; unsigned short Bs[2][4][1026]; } g;
    float ep[32][132];
  };
  __shared__ SMem sm;
  const int tid = threadIdx.x;
  // XCD-chunked bijective remap (8 XCDs)
  int orig = blockIdx.y * gridDim.x + blockIdx.x;
  int nwg = gridDim.x * gridDim.y;
  int q8 = nwg >> 3, r8 = nwg & 7;
  int xcd = orig & 7, idx = orig >> 3;
  int newid = (xcd < r8 ? xcd*(q8+1) : r8*(q8+1) + (xcd-r8)*q8) + idx;
  const int bm = (newid >> 2) * 128;   // gridDim.x == 4
  const int bxi = newid & 3;
  const int bn = bxi * 128;
  const int bx32 = bxi * 32;
  const int lane = tid & 63;
  const int wid = tid >> 6;
  const int wr = wid >> 1;
  const int wcol = wid & 1;
  const int l15 = lane & 15;
  const int l4  = lane >> 4;
  const int tcol = t*32;
  f32x4 acc[4][4] = {};
  for (int kt = 0; kt < ntk; ++kt) {
    const unsigned short* Asrc; int coff;
    if (kt == 0)      { Asrc = P0; coff = tcol; }
    else if (kt == 1) { Asrc = P1; coff = tcol; }
    else if (kt == 2) { Asrc = P2; coff = tcol; }
    else              { Asrc = HB; coff = (kt-3)*32; }
    __syncthreads();
    #pragma unroll
    for (int r2 = 0; r2 < 2; ++r2) {
      int cc = tid + 256*r2;
      int row = cc >> 2, ko = (cc & 3) * 8;
      uint4 vh = make_uint4(0,0,0,0);
      if (bm + row < N) vh = *(const uint4*)(Asrc + (size_t)(bm + row)*384 + coff + ko);
      *(uint4*)&sm.g.As[row][ko] = vh;
      int kg = cc >> 7, col = cc & 127;
      size_t bo = ((size_t)((kt*4 + kg)*GDIM + bn + col))*8;
      *(uint4*)&sm.g.Bs[0][kg][col*8] = *(const uint4*)(BH + bo);
      *(uint4*)&sm.g.Bs[1][kg][col*8] = *(const uint4*)(BL + bo);
    }
    __syncthreads();
    bf16x8 ah[4];
    #pragma unroll
    for (int mi = 0; mi < 4; ++mi) {
      int r = wr*64 + mi*16 + l15;
      ah[mi] = *(const bf16x8*)&sm.g.As[r][l4*8];
    }
    #pragma unroll
    for (int ni = 0; ni < 4; ++ni) {
      int cidx = (wcol*64 + ni*16 + l15)*8;
      bf16x8 bh8 = *(const bf16x8*)&sm.g.Bs[0][l4][cidx];
      bf16x8 bl8 = *(const bf16x8*)&sm.g.Bs[1][l4][cidx];
      #pragma unroll
      for (int mi = 0; mi < 4; ++mi) {
        acc[mi][ni] = __builtin_amdgcn_mfma_f32_16x16x32_bf16(ah[mi], bh8, acc[mi][ni], 0,0,0);
        acc[mi][ni] = __builtin_amdgcn_mfma_f32_16x16x32_bf16(ah[mi], bl8, acc[mi][ni], 0,0,0);
      }
    }
  }
  // ---- epilogue: per mi, stage 32 rows x 128 packed cols, then LSTM ----
  for (int mi = 0; mi < 4; ++mi) {
    __syncthreads();
    #pragma unroll
    for (int ni = 0; ni < 4; ++ni)
      #pragma unroll
      for (int q = 0; q < 4; ++q)
        sm.ep[wr*16 + l4*4 + q][wcol*64 + ni*16 + l15] = acc[mi][ni][q];
    __syncthreads();
    #pragma unroll
    for (int r = 0; r < 4; ++r) {
      int item = tid + 256*r;            // 32 rows x 32 d
      int rloc = item >> 5, dd = item & 31;
      int row = bm + (rloc >> 4)*64 + mi*16 + (rloc & 15);
      if (row >= N) continue;
      int dg = bx32 + dd;
      f32x4 gv = *(f32x4*)&sm.ep[rloc][dd*4];   // i,f,c,o
      float c0 = first ? 0.0f : Cst[(size_t)row*D_HID + dg];
      float gi = gv[0] + bsum[dg]       + wcp[dg]*c0;
      float gf = gv[1] + bsum[128+dg]   + wcp[128+dg]*c0;
      float gc = gv[2] + bsum[256+dg];
      float go = gv[3] + bsum[384+dg];
      float ig = fsig(gi), fg = fsig(gf);
      float cn = fg*c0 + ig*ftanh(gc);
      float og = fsig(go + wcp[256+dg]*cn);
      float hn = og*ftanh(cn);
      Cst[(size_t)row*D_HID + dg] = cn;
      Ht[(size_t)row*D_HID + dg] = hn;
      HG[(size_t)row*D_HID + dg] = f2bf(hn);
    }
  }
}

// ---------------- final tanh + LayerNorm (in place on d_out) ----------------
// float4 per lane (16 B in flight), 32 lanes per 128-elem row, 2 rows/wave.

__global__ __launch_bounds__(256) void k_ln(float* __restrict__ H, const float* __restrict__ gam,
                                            const float* __restrict__ bet, long rows) {
  long row = (long)blockIdx.x*8 + (threadIdx.x >> 5);
  int l32 = threadIdx.x & 31;
  if (row >= rows) return;
  float* p = H + row*(long)D_HID + l32*4;
  float4 v = *(float4*)p;
  float b0 = ftanh(v.x), b1 = ftanh(v.y), b2 = ftanh(v.z), b3 = ftanh(v.w);
  float s = b0 + b1 + b2 + b3;
  float q = b0*b0 + b1*b1 + b2*b2 + b3*b3;
  #pragma unroll
  for (int off = 16; off > 0; off >>= 1) {
    s += __shfl_xor(s, off);
    q += __shfl_xor(q, off);
  }
  float mu  = s * (1.0f/128.0f);
  float var = q * (1.0f/128.0f) - mu*mu;
  float rs  = rsqrtf(var + 1e-5f);
  float4 g = *(const float4*)(gam + l32*4);
  float4 be = *(const float4*)(bet + l32*4);
  float4 o;
  o.x = (b0 - mu)*rs*g.x + be.x;
  o.y = (b1 - mu)*rs*g.y + be.y;
  o.z = (b2 - mu)*rs*g.z + be.z;
  o.w = (b3 - mu)*rs*g.w + be.w;
  *(float4*)p = o;
}

// ---------------- launch ----------------

extern "C" void kernel_launch(void* const* d_in, const int* in_sizes, int n_in,
                              void* d_out, int out_size, void* d_ws, size_t ws_size,
                              hipStream_t stream) {
  const float* x   = (const float*)d_in[0];
  const int*   ei  = (const int*)  d_in[1];
  const float* Wx  = (const float*)d_in[2];
  const float* bx  = (const float*)d_in[3];
  const float* Wh  = (const float*)d_in[4];
  const float* bh  = (const float*)d_in[5];
  const float* wc  = (const float*)d_in[6];
  const float* bg  = (const float*)d_in[7];
  const float* lng = (const float*)d_in[8];
  const float* lnb = (const float*)d_in[9];
  const int N = in_sizes[0] / (C_IN*T_STEPS);
  const int E = in_sizes[1] / 2;
  const int* src = ei;
  const int* dst = ei + E;
  float* Hout = (float*)d_out;

  char* w = (char*)d_ws;
  auto alloc = [&](size_t bytes) -> char* {
    char* p = w; w += (bytes + 255) & ~size_t(255); return p;
  };
  unsigned short* P0 = (unsigned short*)alloc((size_t)N*XW*2);
  unsigned short* P1 = (unsigned short*)alloc((size_t)N*XW*2);
  unsigned short* P2 = (unsigned short*)alloc((size_t)N*XW*2);
  unsigned short* HB = (unsigned short*)alloc((size_t)N*HW*2);
  float* Cst   = (float*)alloc((size_t)N*D_HID*4);
  int*   aux   = (int*)  alloc((size_t)3*N*4);
  float* dis   = (float*)alloc((size_t)N*4);
  int*   rowptr= (int*)  alloc((size_t)(N+1)*4);
  int*   colI  = (int*)  alloc((size_t)E*4);
  float* wvv   = (float*)alloc((size_t)E*4);
  unsigned short* BH = (unsigned short*)alloc((size_t)KTOT*GDIM*2);
  unsigned short* BL = (unsigned short*)alloc((size_t)KTOT*GDIM*2);
  float* bsum  = (float*)alloc((size_t)GDIM*4);
  unsigned short* HG   = (unsigned short*)alloc((size_t)N*D_HID*2);
  unsigned short* Y1HG = (unsigned short*)alloc((size_t)N*D_HID*2);
  if ((size_t)(w - (char*)d_ws) > ws_size) return;

  int* cnt = aux; int* fil = aux + N; int* deg = aux + 2*N;

  k_zero_i<<<cdiv(3L*N,256),256,0,stream>>>(aux, 3*N);
  k_count<<<cdiv(E,256),256,0,stream>>>(src, dst, cnt, deg, E);
  k_dis<<<cdiv(N,256),256,0,stream>>>(deg, dis, N);
  k_scan<<<1,1024,0,stream>>>(cnt, rowptr, N);
  k_fill<<<cdiv(E,256),256,0,stream>>>(src, dst, rowptr, fil, dis, colI, wvv, E);
  k_packB<<<cdiv((long)KTOT*GDIM,256),256,0,stream>>>(Wx, Wh, BH, BL);
  k_bias<<<2,256,0,stream>>>(bx, bh, bg, bsum);

  // x-side for ALL timesteps: P0 = x, P1 = L@P0, P2 = L@P1  (3 dispatches)
  k_xt_all<<<cdiv((long)N*XW,256),256,0,stream>>>(x, P0, (long)N*XW);
  k_spmm_x<<<cdiv((long)N*96,256),256,0,stream>>>(rowptr, colI, wvv, P0, P1, N);
  k_spmm_x<<<cdiv((long)N*96,256),256,0,stream>>>(rowptr, colI, wvv, P1, P2, N);

  dim3 ggrid(GDIM/128, cdiv(N,128));
  dim3 sgrid(4, cdiv(N,16));
  for (int t = 0; t < T_STEPS; ++t) {
    // h-side basis: h copied to HB[0:128) by spmm #1; y1h -> [128,256); y2h -> [256,384)
    if (t > 0) {
      k_spmm_h<<<sgrid,256,0,stream>>>(rowptr, colI, wvv,
          HG, HB, Y1HG, 128, 0, N);
      k_spmm_h<<<sgrid,256,0,stream>>>(rowptr, colI, wvv,
          Y1HG, HB, nullptr, 256, -1, N);
    }
    // fused gates GEMM (bf16x2, gate-interleaved B) + LSTM epilogue
    int ntk = (t == 0) ? 3 : KTOT/32;   // t=0: h-cols zero, skip those k-tiles
    k_gemm_lstm<<<ggrid,256,0,stream>>>(P0, P1, P2, HB, BH, BL, bsum, wc,
        Cst, Hout + (size_t)t*N*D_HID, HG, N, t == 0 ? 1 : 0, ntk, t);
  }
  k_ln<<<cdiv((long)T_STEPS*N,8),256,0,stream>>>(Hout, lng, lnb, (long)T_STEPS*N);
}

// Round 15
// 3786.811 us; speedup vs baseline: 1.0146x; 1.0146x over previous
//
#include <hip/hip_runtime.h>
#include <math.h>

static constexpr int C_IN    = 32;
static constexpr int T_STEPS = 12;
static constexpr int D_HID   = 128;
static constexpr int KTOT    = 3*C_IN + 3*D_HID;  // 480
static constexpr int GDIM    = 4*D_HID;           // 512
static constexpr int XW      = T_STEPS*C_IN;      // 384: x-plane row width
static constexpr int HW      = 3*D_HID;           // 384: h-basis row width

static inline int cdiv(long a, int b) { return (int)((a + b - 1) / b); }

typedef __attribute__((ext_vector_type(8))) short bf16x8;
typedef __attribute__((ext_vector_type(4))) float f32x4;

__device__ __forceinline__ float bf2f(unsigned int u16) {
  union { unsigned int u; float f; } v; v.u = u16 << 16; return v.f;
}
__device__ __forceinline__ unsigned short f2bf(float f) {
  union { float f; unsigned int u; } v; v.f = f;
  unsigned int u = v.u + 0x7fffu + ((v.u >> 16) & 1u);  // RNE
  return (unsigned short)(u >> 16);
}
__device__ __forceinline__ void split2(float a, unsigned short& h, unsigned short& l) {
  h = f2bf(a);
  l = f2bf(a - bf2f(h));
}
__device__ __forceinline__ float fsig(float x) { return 1.0f/(1.0f + __expf(-x)); }
__device__ __forceinline__ float ftanh(float x) {
  float e = __expf(2.0f*x);
  return 1.0f - 2.0f/(e + 1.0f);
}

// ---------------- CSR build ----------------

__global__ void k_zero_i(int* __restrict__ p, int n) {
  int i = blockIdx.x*blockDim.x + threadIdx.x;
  if (i < n) p[i] = 0;
}

__global__ void k_count(const int* __restrict__ src, const int* __restrict__ dst,
                        int* __restrict__ cnt, int* __restrict__ deg, int E) {
  int e = blockIdx.x*blockDim.x + threadIdx.x;
  if (e < E) {
    atomicAdd(&cnt[dst[e]], 1);
    atomicAdd(&deg[src[e]], 1);
  }
}

__global__ void k_dis(const int* __restrict__ deg, float* __restrict__ dis, int n) {
  int i = blockIdx.x*blockDim.x + threadIdx.x;
  if (i < n) {
    int d = deg[i];
    dis[i] = d > 0 ? rsqrtf((float)d) : 0.0f;
  }
}

__global__ __launch_bounds__(1024) void k_scan(const int* __restrict__ cnt,
                                               int* __restrict__ rowptr, int n) {
  __shared__ int wsum[16];
  __shared__ int carry_s;
  int tid = threadIdx.x; int lane = tid & 63; int wv_ = tid >> 6;
  if (tid == 0) { carry_s = 0; rowptr[0] = 0; }
  __syncthreads();
  for (int base = 0; base < n; base += 1024) {
    int i = base + tid;
    int s = (i < n) ? cnt[i] : 0;
    #pragma unroll
    for (int off = 1; off < 64; off <<= 1) {
      int t = __shfl_up(s, off);
      if (lane >= off) s += t;
    }
    if (lane == 63) wsum[wv_] = s;
    __syncthreads();
    if (tid < 16) {
      int ws = wsum[tid];
      #pragma unroll
      for (int off = 1; off < 16; off <<= 1) {
        int t = __shfl_up(ws, off);
        if (tid >= off) ws += t;
      }
      wsum[tid] = ws;
    }
    __syncthreads();
    int offw = carry_s + (wv_ > 0 ? wsum[wv_-1] : 0);
    if (i < n) rowptr[i+1] = offw + s;
    __syncthreads();
    if (tid == 0) carry_s = carry_s + wsum[15];
    __syncthreads();
  }
}

__global__ void k_fill(const int* __restrict__ src, const int* __restrict__ dst,
                       const int* __restrict__ rowptr, int* __restrict__ fil,
                       const float* __restrict__ dis,
                       int* __restrict__ colI, float* __restrict__ wvv, int E) {
  int e = blockIdx.x*blockDim.x + threadIdx.x;
  if (e < E) {
    int d = dst[e], s = src[e];
    int p = rowptr[d] + atomicAdd(&fil[d], 1);
    colI[p] = s;
    wvv[p] = -dis[s] * dis[d];
  }
}

// ---------------- weight packing ----------------
// Column permutation p = 4*d + g (gate-interleaved). Chebyshev refold:
// basis [v, y1=Lv, y2=L(Lv)] with weights [W0-W2, W1, 2*W2].
// k8-interleave: element (kk,p) at ((kt*4+kg)*512+p)*8+i, kk=kt*32+kg*8+i.

__global__ void k_packB(const float* __restrict__ Wx, const float* __restrict__ Wh,
                        unsigned short* __restrict__ BH, unsigned short* __restrict__ BL) {
  int idx = blockIdx.x*blockDim.x + threadIdx.x;
  if (idx >= KTOT*GDIM) return;
  int kk = idx / GDIM, p = idx % GDIM;
  int g = p & 3, d = p >> 2;
  float v;
  if (kk < 96) {
    int k3 = kk >> 5, c = kk & 31;
    auto wx = [&](int k) { return Wx[((((size_t)g*3 + k)*32 + c) << 7) + d]; };
    v = (k3 == 0) ? wx(0) - wx(2) : (k3 == 1) ? wx(1) : 2.0f*wx(2);
  } else {
    int kk2 = kk - 96;
    int k3 = kk2 >> 7, j = kk2 & 127;
    auto wh = [&](int k) { return Wh[((((size_t)g*3 + k)*128 + j) << 7) + d]; };
    v = (k3 == 0) ? wh(0) - wh(2) : (k3 == 1) ? wh(1) : 2.0f*wh(2);
  }
  unsigned short h, l; split2(v, h, l);
  int kt = kk >> 5, kg = (kk >> 3) & 3, i = kk & 7;
  size_t o = ((size_t)((kt*4 + kg)*GDIM + p))*8 + i;
  BH[o] = h; BL[o] = l;
}

__global__ void k_bias(const float* __restrict__ bx, const float* __restrict__ bh,
                       const float* __restrict__ bg, float* __restrict__ bsum) {
  int i = blockIdx.x*blockDim.x + threadIdx.x;
  if (i < GDIM) bsum[i] = bx[i] + bh[i] + bg[i];
}

// ---------------- staging ----------------

// P0[n][t*32+c] = bf16(x[n][c][t])  for all t at once
__global__ void k_xt_all(const float* __restrict__ x, unsigned short* __restrict__ P0,
                         long total) {
  long i = (long)blockIdx.x*blockDim.x + threadIdx.x;   // ((n*12+t)*32+c)
  if (i >= total) return;
  int c = (int)(i & 31);
  long nt = i >> 5;
  int t = (int)(nt % T_STEPS);
  long n = nt / T_STEPS;
  float v = x[(n*C_IN + c)*T_STEPS + t];
  P0[n*XW + t*C_IN + c] = f2bf(v);
}

// DST[n][0:384) = L_hat @ SRC   (compact planes, 96 uint2-lanes per node)
__global__ void k_spmm_x(const int* __restrict__ rowptr, const int* __restrict__ colI,
                         const float* __restrict__ wvv,
                         const unsigned short* __restrict__ SRC,
                         unsigned short* __restrict__ DST, int n) {
  int gt = blockIdx.x*blockDim.x + threadIdx.x;
  int node = gt / 96;
  int lane = gt - node*96;
  if (node >= n) return;
  const uint2* gp = (const uint2*)SRC;
  float a0 = 0.f, a1 = 0.f, a2 = 0.f, a3 = 0.f;
  int r0 = rowptr[node], r1 = rowptr[node+1];
  int e = r0;
  for (; e + 4 <= r1; e += 4) {
    int s0 = colI[e], s1 = colI[e+1], s2 = colI[e+2], s3 = colI[e+3];
    float w0 = wvv[e], w1 = wvv[e+1], w2 = wvv[e+2], w3 = wvv[e+3];
    uint2 u0 = gp[(size_t)s0*96 + lane];
    uint2 u1 = gp[(size_t)s1*96 + lane];
    uint2 u2 = gp[(size_t)s2*96 + lane];
    uint2 u3 = gp[(size_t)s3*96 + lane];
    a0 += w0*bf2f(u0.x & 0xffffu) + w1*bf2f(u1.x & 0xffffu)
        + w2*bf2f(u2.x & 0xffffu) + w3*bf2f(u3.x & 0xffffu);
    a1 += w0*bf2f(u0.x >> 16)     + w1*bf2f(u1.x >> 16)
        + w2*bf2f(u2.x >> 16)     + w3*bf2f(u3.x >> 16);
    a2 += w0*bf2f(u0.y & 0xffffu) + w1*bf2f(u1.y & 0xffffu)
        + w2*bf2f(u2.y & 0xffffu) + w3*bf2f(u3.y & 0xffffu);
    a3 += w0*bf2f(u0.y >> 16)     + w1*bf2f(u1.y >> 16)
        + w2*bf2f(u2.y >> 16)     + w3*bf2f(u3.y >> 16);
  }
  for (; e < r1; ++e) {
    int s = colI[e]; float w = wvv[e];
    uint2 u = gp[(size_t)s*96 + lane];
    a0 += w*bf2f(u.x & 0xffffu);
    a1 += w*bf2f(u.x >> 16);
    a2 += w*bf2f(u.y & 0xffffu);
    a3 += w*bf2f(u.y >> 16);
  }
  uint2 hw;
  hw.x = (unsigned int)f2bf(a0) | ((unsigned int)f2bf(a1) << 16);
  hw.y = (unsigned int)f2bf(a2) | ((unsigned int)f2bf(a3) << 16);
  ((uint2*)DST)[(size_t)node*96 + lane] = hw;
}

// h-side: y = L_hat @ GSRC (compact [n][128]); r11 structure verbatim —
// 32 lanes/node, uint2/lane, unroll-4 (best measured; r12/r13/r14 variants
// were neutral-to-worse: the gather sits at the cache-system ceiling).
__global__ void k_spmm_h(const int* __restrict__ rowptr, const int* __restrict__ colI,
                         const float* __restrict__ wvv,
                         const unsigned short* __restrict__ GSRC,
                         unsigned short* __restrict__ HB,
                         unsigned short* __restrict__ GOUT, int colO, int selfCol, int n) {
  int gt = blockIdx.x*blockDim.x + threadIdx.x;
  int node = gt >> 5;
  int lane = gt & 31;
  if (node >= n) return;
  const uint2* gp = (const uint2*)GSRC;
  if (selfCol >= 0) {
    uint2 own = gp[(size_t)node*32 + lane];
    ((uint2*)HB)[(((size_t)node*HW + selfCol) >> 2) + lane] = own;
  }
  float a0 = 0.f, a1 = 0.f, a2 = 0.f, a3 = 0.f;
  int r0 = rowptr[node], r1 = rowptr[node+1];
  int e = r0;
  for (; e + 4 <= r1; e += 4) {
    int s0 = colI[e], s1 = colI[e+1], s2 = colI[e+2], s3 = colI[e+3];
    float w0 = wvv[e], w1 = wvv[e+1], w2 = wvv[e+2], w3 = wvv[e+3];
    uint2 u0 = gp[(size_t)s0*32 + lane];
    uint2 u1 = gp[(size_t)s1*32 + lane];
    uint2 u2 = gp[(size_t)s2*32 + lane];
    uint2 u3 = gp[(size_t)s3*32 + lane];
    a0 += w0*bf2f(u0.x & 0xffffu) + w1*bf2f(u1.x & 0xffffu)
        + w2*bf2f(u2.x & 0xffffu) + w3*bf2f(u3.x & 0xffffu);
    a1 += w0*bf2f(u0.x >> 16)     + w1*bf2f(u1.x >> 16)
        + w2*bf2f(u2.x >> 16)     + w3*bf2f(u3.x >> 16);
    a2 += w0*bf2f(u0.y & 0xffffu) + w1*bf2f(u1.y & 0xffffu)
        + w2*bf2f(u2.y & 0xffffu) + w3*bf2f(u3.y & 0xffffu);
    a3 += w0*bf2f(u0.y >> 16)     + w1*bf2f(u1.y >> 16)
        + w2*bf2f(u2.y >> 16)     + w3*bf2f(u3.y >> 16);
  }
  for (; e < r1; ++e) {
    int s = colI[e]; float w = wvv[e];
    uint2 u = gp[(size_t)s*32 + lane];
    a0 += w*bf2f(u.x & 0xffffu);
    a1 += w*bf2f(u.x >> 16);
    a2 += w*bf2f(u.y & 0xffffu);
    a3 += w*bf2f(u.y >> 16);
  }
  uint2 hw;
  hw.x = (unsigned int)f2bf(a0) | ((unsigned int)f2bf(a1) << 16);
  hw.y = (unsigned int)f2bf(a2) | ((unsigned int)f2bf(a3) << 16);
  ((uint2*)HB)[(((size_t)node*HW + colO) >> 2) + lane] = hw;
  if (GOUT) ((uint2*)GOUT)[(size_t)node*32 + lane] = hw;
}

// ---------------- fused MFMA GEMM + LSTM cell ----------------
// BM=256 x 128 packed cols, 8 waves (512 thr), ~37.9 KB LDS -> 4 blocks/CU
// = 32 waves/CU (occupancy UP vs r11's 20; r10's failure was occupancy DOWN).
// Per-wave tile stays 64x64 (acc[4][4], VGPR unchanged). bf16x2.
// Bank-conflict-free: A rows 42 shorts, B planes 1026 shorts.
// A k-tiles: kt 0,1,2 from P0/P1/P2 (+t*32), kt 3..14 from HB ((kt-3)*32).
// XCD-chunked bijective swizzle. Epilogue writes h ONLY to HG (race-free).

__global__ __launch_bounds__(512) void k_gemm_lstm(
    const unsigned short* __restrict__ P0, const unsigned short* __restrict__ P1,
    const unsigned short* __restrict__ P2, const unsigned short* __restrict__ HB,
    const unsigned short* __restrict__ BH, const unsigned short* __restrict__ BL,
    const float* __restrict__ bsum, const float* __restrict__ wcp,
    float* __restrict__ Cst, float* __restrict__ Ht,
    unsigned short* __restrict__ HG,
    int N, int first, int ntk, int t) {
  union SMem {
    struct { unsigned short As[256][42]; unsigned short Bs[2][4][1026]; } g;
    float ep[64][132];
  };
  __shared__ SMem sm;
  const int tid = threadIdx.x;
  // XCD-chunked bijective remap (8 XCDs)
  int orig = blockIdx.y * gridDim.x + blockIdx.x;
  int nwg = gridDim.x * gridDim.y;
  int q8 = nwg >> 3, r8 = nwg & 7;
  int xcd = orig & 7, idx = orig >> 3;
  int newid = (xcd < r8 ? xcd*(q8+1) : r8*(q8+1) + (xcd-r8)*q8) + idx;
  const int bm = (newid >> 2) * 256;   // gridDim.x == 4
  const int bxi = newid & 3;
  const int bn = bxi * 128;
  const int bx32 = bxi * 32;
  const int lane = tid & 63;
  const int wid = tid >> 6;            // 0..7
  const int wr = wid >> 1;             // 0..3 (64-row band)
  const int wcol = wid & 1;            // 0..1 (64-col band)
  const int l15 = lane & 15;
  const int l4  = lane >> 4;
  const int tcol = t*32;
  f32x4 acc[4][4] = {};
  for (int kt = 0; kt < ntk; ++kt) {
    const unsigned short* Asrc; int coff;
    if (kt == 0)      { Asrc = P0; coff = tcol; }
    else if (kt == 1) { Asrc = P1; coff = tcol; }
    else if (kt == 2) { Asrc = P2; coff = tcol; }
    else              { Asrc = HB; coff = (kt-3)*32; }
    __syncthreads();
    // A tile: 256 rows x 32 k = 1024 uint4, 2 per thread
    #pragma unroll
    for (int r2 = 0; r2 < 2; ++r2) {
      int cc = tid + 512*r2;
      int row = cc >> 2, ko = (cc & 3) * 8;
      uint4 vh = make_uint4(0,0,0,0);
      if (bm + row < N) vh = *(const uint4*)(Asrc + (size_t)(bm + row)*384 + coff + ko);
      *(uint4*)&sm.g.As[row][ko] = vh;
    }
    // B tile: 4 kg x 128 cols, hi+lo; 512 positions, 1 per thread
    {
      int kg = tid >> 7, col = tid & 127;
      size_t bo = ((size_t)((kt*4 + kg)*GDIM + bn + col))*8;
      *(uint4*)&sm.g.Bs[0][kg][col*8] = *(const uint4*)(BH + bo);
      *(uint4*)&sm.g.Bs[1][kg][col*8] = *(const uint4*)(BL + bo);
    }
    __syncthreads();
    bf16x8 ah[4];
    #pragma unroll
    for (int mi = 0; mi < 4; ++mi) {
      int r = wr*64 + mi*16 + l15;
      ah[mi] = *(const bf16x8*)&sm.g.As[r][l4*8];
    }
    #pragma unroll
    for (int ni = 0; ni < 4; ++ni) {
      int cidx = (wcol*64 + ni*16 + l15)*8;
      bf16x8 bh8 = *(const bf16x8*)&sm.g.Bs[0][l4][cidx];
      bf16x8 bl8 = *(const bf16x8*)&sm.g.Bs[1][l4][cidx];
      #pragma unroll
      for (int mi = 0; mi < 4; ++mi) {
        acc[mi][ni] = __builtin_amdgcn_mfma_f32_16x16x32_bf16(ah[mi], bh8, acc[mi][ni], 0,0,0);
        acc[mi][ni] = __builtin_amdgcn_mfma_f32_16x16x32_bf16(ah[mi], bl8, acc[mi][ni], 0,0,0);
      }
    }
  }
  // ---- epilogue: per mi, stage 64 rows x 128 packed cols, then LSTM ----
  for (int mi = 0; mi < 4; ++mi) {
    __syncthreads();
    #pragma unroll
    for (int ni = 0; ni < 4; ++ni)
      #pragma unroll
      for (int q = 0; q < 4; ++q)
        sm.ep[wr*16 + l4*4 + q][wcol*64 + ni*16 + l15] = acc[mi][ni][q];
    __syncthreads();
    #pragma unroll
    for (int r = 0; r < 4; ++r) {
      int item = tid + 512*r;            // 64 rows x 32 d = 2048 items
      int rloc = item >> 5, dd = item & 31;
      int row = bm + (rloc >> 4)*64 + mi*16 + (rloc & 15);
      if (row >= N) continue;
      int dg = bx32 + dd;
      f32x4 gv = *(f32x4*)&sm.ep[rloc][dd*4];   // i,f,c,o
      float c0 = first ? 0.0f : Cst[(size_t)row*D_HID + dg];
      float gi = gv[0] + bsum[dg]       + wcp[dg]*c0;
      float gf = gv[1] + bsum[128+dg]   + wcp[128+dg]*c0;
      float gc = gv[2] + bsum[256+dg];
      float go = gv[3] + bsum[384+dg];
      float ig = fsig(gi), fg = fsig(gf);
      float cn = fg*c0 + ig*ftanh(gc);
      float og = fsig(go + wcp[256+dg]*cn);
      float hn = og*ftanh(cn);
      Cst[(size_t)row*D_HID + dg] = cn;
      Ht[(size_t)row*D_HID + dg] = hn;
      HG[(size_t)row*D_HID + dg] = f2bf(hn);
    }
  }
}

// ---------------- final tanh + LayerNorm (in place on d_out) ----------------
// float4 per lane, 32 lanes per 128-elem row, 2 rows/wave.

__global__ __launch_bounds__(256) void k_ln(float* __restrict__ H, const float* __restrict__ gam,
                                            const float* __restrict__ bet, long rows) {
  long row = (long)blockIdx.x*8 + (threadIdx.x >> 5);
  int l32 = threadIdx.x & 31;
  if (row >= rows) return;
  float* p = H + row*(long)D_HID + l32*4;
  float4 v = *(float4*)p;
  float b0 = ftanh(v.x), b1 = ftanh(v.y), b2 = ftanh(v.z), b3 = ftanh(v.w);
  float s = b0 + b1 + b2 + b3;
  float q = b0*b0 + b1*b1 + b2*b2 + b3*b3;
  #pragma unroll
  for (int off = 16; off > 0; off >>= 1) {
    s += __shfl_xor(s, off);
    q += __shfl_xor(q, off);
  }
  float mu  = s * (1.0f/128.0f);
  float var = q * (1.0f/128.0f) - mu*mu;
  float rs  = rsqrtf(var + 1e-5f);
  float4 g = *(const float4*)(gam + l32*4);
  float4 be = *(const float4*)(bet + l32*4);
  float4 o;
  o.x = (b0 - mu)*rs*g.x + be.x;
  o.y = (b1 - mu)*rs*g.y + be.y;
  o.z = (b2 - mu)*rs*g.z + be.z;
  o.w = (b3 - mu)*rs*g.w + be.w;
  *(float4*)p = o;
}

// ---------------- launch ----------------

extern "C" void kernel_launch(void* const* d_in, const int* in_sizes, int n_in,
                              void* d_out, int out_size, void* d_ws, size_t ws_size,
                              hipStream_t stream) {
  const float* x   = (const float*)d_in[0];
  const int*   ei  = (const int*)  d_in[1];
  const float* Wx  = (const float*)d_in[2];
  const float* bx  = (const float*)d_in[3];
  const float* Wh  = (const float*)d_in[4];
  const float* bh  = (const float*)d_in[5];
  const float* wc  = (const float*)d_in[6];
  const float* bg  = (const float*)d_in[7];
  const float* lng = (const float*)d_in[8];
  const float* lnb = (const float*)d_in[9];
  const int N = in_sizes[0] / (C_IN*T_STEPS);
  const int E = in_sizes[1] / 2;
  const int* src = ei;
  const int* dst = ei + E;
  float* Hout = (float*)d_out;

  char* w = (char*)d_ws;
  auto alloc = [&](size_t bytes) -> char* {
    char* p = w; w += (bytes + 255) & ~size_t(255); return p;
  };
  unsigned short* P0 = (unsigned short*)alloc((size_t)N*XW*2);
  unsigned short* P1 = (unsigned short*)alloc((size_t)N*XW*2);
  unsigned short* P2 = (unsigned short*)alloc((size_t)N*XW*2);
  unsigned short* HB = (unsigned short*)alloc((size_t)N*HW*2);
  float* Cst   = (float*)alloc((size_t)N*D_HID*4);
  int*   aux   = (int*)  alloc((size_t)3*N*4);
  float* dis   = (float*)alloc((size_t)N*4);
  int*   rowptr= (int*)  alloc((size_t)(N+1)*4);
  int*   colI  = (int*)  alloc((size_t)E*4);
  float* wvv   = (float*)alloc((size_t)E*4);
  unsigned short* BH = (unsigned short*)alloc((size_t)KTOT*GDIM*2);
  unsigned short* BL = (unsigned short*)alloc((size_t)KTOT*GDIM*2);
  float* bsum  = (float*)alloc((size_t)GDIM*4);
  unsigned short* HG   = (unsigned short*)alloc((size_t)N*D_HID*2);
  unsigned short* Y1HG = (unsigned short*)alloc((size_t)N*D_HID*2);
  if ((size_t)(w - (char*)d_ws) > ws_size) return;

  int* cnt = aux; int* fil = aux + N; int* deg = aux + 2*N;

  k_zero_i<<<cdiv(3L*N,256),256,0,stream>>>(aux, 3*N);
  k_count<<<cdiv(E,256),256,0,stream>>>(src, dst, cnt, deg, E);
  k_dis<<<cdiv(N,256),256,0,stream>>>(deg, dis, N);
  k_scan<<<1,1024,0,stream>>>(cnt, rowptr, N);
  k_fill<<<cdiv(E,256),256,0,stream>>>(src, dst, rowptr, fil, dis, colI, wvv, E);
  k_packB<<<cdiv((long)KTOT*GDIM,256),256,0,stream>>>(Wx, Wh, BH, BL);
  k_bias<<<2,256,0,stream>>>(bx, bh, bg, bsum);

  // x-side for ALL timesteps: P0 = x, P1 = L@P0, P2 = L@P1  (3 dispatches)
  k_xt_all<<<cdiv((long)N*XW,256),256,0,stream>>>(x, P0, (long)N*XW);
  k_spmm_x<<<cdiv((long)N*96,256),256,0,stream>>>(rowptr, colI, wvv, P0, P1, N);
  k_spmm_x<<<cdiv((long)N*96,256),256,0,stream>>>(rowptr, colI, wvv, P1, P2, N);

  dim3 ggrid(GDIM/128, cdiv(N,256));
  for (int t = 0; t < T_STEPS; ++t) {
    // h-side basis: h copied to HB[0:128) by spmm #1; y1h -> [128,256); y2h -> [256,384)
    if (t > 0) {
      k_spmm_h<<<cdiv((long)N*32,256),256,0,stream>>>(rowptr, colI, wvv,
          HG, HB, Y1HG, 128, 0, N);
      k_spmm_h<<<cdiv((long)N*32,256),256,0,stream>>>(rowptr, colI, wvv,
          Y1HG, HB, nullptr, 256, -1, N);
    }
    // fused gates GEMM (bf16x2, gate-interleaved B) + LSTM epilogue
    int ntk = (t == 0) ? 3 : KTOT/32;   // t=0: h-cols zero, skip those k-tiles
    k_gemm_lstm<<<ggrid,512,0,stream>>>(P0, P1, P2, HB, BH, BL, bsum, wc,
        Cst, Hout + (size_t)t*N*D_HID, HG, N, t == 0 ? 1 : 0, ntk, t);
  }
  k_ln<<<cdiv((long)T_STEPS*N,8),256,0,stream>>>(Hout, lng, lnb, (long)T_STEPS*N);
}

// Round 16
// 3180.116 us; speedup vs baseline: 1.2082x; 1.1908x over previous
//
#include <hip/hip_runtime.h>
#include <math.h>

static constexpr int C_IN    = 32;
static constexpr int T_STEPS = 12;
static constexpr int D_HID   = 128;
static constexpr int KTOT    = 3*C_IN + 3*D_HID;  // 480
static constexpr int GDIM    = 4*D_HID;           // 512
static constexpr int XW      = T_STEPS*C_IN;      // 384: x-plane row width
static constexpr int HW      = 3*D_HID;           // 384: h-basis row width

static inline int cdiv(long a, int b) { return (int)((a + b - 1) / b); }

typedef __attribute__((ext_vector_type(8))) short bf16x8;
typedef __attribute__((ext_vector_type(4))) float f32x4;

__device__ __forceinline__ float bf2f(unsigned int u16) {
  union { unsigned int u; float f; } v; v.u = u16 << 16; return v.f;
}
__device__ __forceinline__ unsigned short f2bf(float f) {
  union { float f; unsigned int u; } v; v.f = f;
  unsigned int u = v.u + 0x7fffu + ((v.u >> 16) & 1u);  // RNE
  return (unsigned short)(u >> 16);
}
__device__ __forceinline__ void split2(float a, unsigned short& h, unsigned short& l) {
  h = f2bf(a);
  l = f2bf(a - bf2f(h));
}
__device__ __forceinline__ float fsig(float x) { return 1.0f/(1.0f + __expf(-x)); }
__device__ __forceinline__ float ftanh(float x) {
  float e = __expf(2.0f*x);
  return 1.0f - 2.0f/(e + 1.0f);
}

// ---------------- CSR build ----------------

__global__ void k_zero_i(int* __restrict__ p, int n) {
  int i = blockIdx.x*blockDim.x + threadIdx.x;
  if (i < n) p[i] = 0;
}

__global__ void k_count(const int* __restrict__ src, const int* __restrict__ dst,
                        int* __restrict__ cnt, int* __restrict__ deg, int E) {
  int e = blockIdx.x*blockDim.x + threadIdx.x;
  if (e < E) {
    atomicAdd(&cnt[dst[e]], 1);
    atomicAdd(&deg[src[e]], 1);
  }
}

__global__ void k_dis(const int* __restrict__ deg, float* __restrict__ dis, int n) {
  int i = blockIdx.x*blockDim.x + threadIdx.x;
  if (i < n) {
    int d = deg[i];
    dis[i] = d > 0 ? rsqrtf((float)d) : 0.0f;
  }
}

__global__ __launch_bounds__(1024) void k_scan(const int* __restrict__ cnt,
                                               int* __restrict__ rowptr, int n) {
  __shared__ int wsum[16];
  __shared__ int carry_s;
  int tid = threadIdx.x; int lane = tid & 63; int wv_ = tid >> 6;
  if (tid == 0) { carry_s = 0; rowptr[0] = 0; }
  __syncthreads();
  for (int base = 0; base < n; base += 1024) {
    int i = base + tid;
    int s = (i < n) ? cnt[i] : 0;
    #pragma unroll
    for (int off = 1; off < 64; off <<= 1) {
      int t = __shfl_up(s, off);
      if (lane >= off) s += t;
    }
    if (lane == 63) wsum[wv_] = s;
    __syncthreads();
    if (tid < 16) {
      int ws = wsum[tid];
      #pragma unroll
      for (int off = 1; off < 16; off <<= 1) {
        int t = __shfl_up(ws, off);
        if (tid >= off) ws += t;
      }
      wsum[tid] = ws;
    }
    __syncthreads();
    int offw = carry_s + (wv_ > 0 ? wsum[wv_-1] : 0);
    if (i < n) rowptr[i+1] = offw + s;
    __syncthreads();
    if (tid == 0) carry_s = carry_s + wsum[15];
    __syncthreads();
  }
}

__global__ void k_fill(const int* __restrict__ src, const int* __restrict__ dst,
                       const int* __restrict__ rowptr, int* __restrict__ fil,
                       const float* __restrict__ dis,
                       int* __restrict__ colI, float* __restrict__ wvv, int E) {
  int e = blockIdx.x*blockDim.x + threadIdx.x;
  if (e < E) {
    int d = dst[e], s = src[e];
    int p = rowptr[d] + atomicAdd(&fil[d], 1);
    colI[p] = s;
    wvv[p] = -dis[s] * dis[d];
  }
}

// ---------------- weight packing ----------------
// Column permutation p = 4*d + g (gate-interleaved). Chebyshev refold:
// basis [v, y1=Lv, y2=L(Lv)] with weights [W0-W2, W1, 2*W2].
// k8-interleave: element (kk,p) at ((kt*4+kg)*512+p)*8+i, kk=kt*32+kg*8+i.

__global__ void k_packB(const float* __restrict__ Wx, const float* __restrict__ Wh,
                        unsigned short* __restrict__ BH, unsigned short* __restrict__ BL) {
  int idx = blockIdx.x*blockDim.x + threadIdx.x;
  if (idx >= KTOT*GDIM) return;
  int kk = idx / GDIM, p = idx % GDIM;
  int g = p & 3, d = p >> 2;
  float v;
  if (kk < 96) {
    int k3 = kk >> 5, c = kk & 31;
    auto wx = [&](int k) { return Wx[((((size_t)g*3 + k)*32 + c) << 7) + d]; };
    v = (k3 == 0) ? wx(0) - wx(2) : (k3 == 1) ? wx(1) : 2.0f*wx(2);
  } else {
    int kk2 = kk - 96;
    int k3 = kk2 >> 7, j = kk2 & 127;
    auto wh = [&](int k) { return Wh[((((size_t)g*3 + k)*128 + j) << 7) + d]; };
    v = (k3 == 0) ? wh(0) - wh(2) : (k3 == 1) ? wh(1) : 2.0f*wh(2);
  }
  unsigned short h, l; split2(v, h, l);
  int kt = kk >> 5, kg = (kk >> 3) & 3, i = kk & 7;
  size_t o = ((size_t)((kt*4 + kg)*GDIM + p))*8 + i;
  BH[o] = h; BL[o] = l;
}

__global__ void k_bias(const float* __restrict__ bx, const float* __restrict__ bh,
                       const float* __restrict__ bg, float* __restrict__ bsum) {
  int i = blockIdx.x*blockDim.x + threadIdx.x;
  if (i < GDIM) bsum[i] = bx[i] + bh[i] + bg[i];
}

// ---------------- staging ----------------

// P0[n][t*32+c] = bf16(x[n][c][t])  for all t at once
__global__ void k_xt_all(const float* __restrict__ x, unsigned short* __restrict__ P0,
                         long total) {
  long i = (long)blockIdx.x*blockDim.x + threadIdx.x;   // ((n*12+t)*32+c)
  if (i >= total) return;
  int c = (int)(i & 31);
  long nt = i >> 5;
  int t = (int)(nt % T_STEPS);
  long n = nt / T_STEPS;
  float v = x[(n*C_IN + c)*T_STEPS + t];
  P0[n*XW + t*C_IN + c] = f2bf(v);
}

// DST[n][0:384) = L_hat @ SRC   (compact planes, 96 uint2-lanes per node)
__global__ void k_spmm_x(const int* __restrict__ rowptr, const int* __restrict__ colI,
                         const float* __restrict__ wvv,
                         const unsigned short* __restrict__ SRC,
                         unsigned short* __restrict__ DST, int n) {
  int gt = blockIdx.x*blockDim.x + threadIdx.x;
  int node = gt / 96;
  int lane = gt - node*96;
  if (node >= n) return;
  const uint2* gp = (const uint2*)SRC;
  float a0 = 0.f, a1 = 0.f, a2 = 0.f, a3 = 0.f;
  int r0 = rowptr[node], r1 = rowptr[node+1];
  int e = r0;
  for (; e + 4 <= r1; e += 4) {
    int s0 = colI[e], s1 = colI[e+1], s2 = colI[e+2], s3 = colI[e+3];
    float w0 = wvv[e], w1 = wvv[e+1], w2 = wvv[e+2], w3 = wvv[e+3];
    uint2 u0 = gp[(size_t)s0*96 + lane];
    uint2 u1 = gp[(size_t)s1*96 + lane];
    uint2 u2 = gp[(size_t)s2*96 + lane];
    uint2 u3 = gp[(size_t)s3*96 + lane];
    a0 += w0*bf2f(u0.x & 0xffffu) + w1*bf2f(u1.x & 0xffffu)
        + w2*bf2f(u2.x & 0xffffu) + w3*bf2f(u3.x & 0xffffu);
    a1 += w0*bf2f(u0.x >> 16)     + w1*bf2f(u1.x >> 16)
        + w2*bf2f(u2.x >> 16)     + w3*bf2f(u3.x >> 16);
    a2 += w0*bf2f(u0.y & 0xffffu) + w1*bf2f(u1.y & 0xffffu)
        + w2*bf2f(u2.y & 0xffffu) + w3*bf2f(u3.y & 0xffffu);
    a3 += w0*bf2f(u0.y >> 16)     + w1*bf2f(u1.y >> 16)
        + w2*bf2f(u2.y >> 16)     + w3*bf2f(u3.y >> 16);
  }
  for (; e < r1; ++e) {
    int s = colI[e]; float w = wvv[e];
    uint2 u = gp[(size_t)s*96 + lane];
    a0 += w*bf2f(u.x & 0xffffu);
    a1 += w*bf2f(u.x >> 16);
    a2 += w*bf2f(u.y & 0xffffu);
    a3 += w*bf2f(u.y >> 16);
  }
  uint2 hw;
  hw.x = (unsigned int)f2bf(a0) | ((unsigned int)f2bf(a1) << 16);
  hw.y = (unsigned int)f2bf(a2) | ((unsigned int)f2bf(a3) << 16);
  ((uint2*)DST)[(size_t)node*96 + lane] = hw;
}

// h-side: y = L_hat @ GSRC (compact [n][128]); r11 structure verbatim —
// 32 lanes/node, uint2/lane, unroll-4 (best measured; r12/r13/r14 variants
// were neutral-to-worse: the gather sits at the cache-system ceiling).
__global__ void k_spmm_h(const int* __restrict__ rowptr, const int* __restrict__ colI,
                         const float* __restrict__ wvv,
                         const unsigned short* __restrict__ GSRC,
                         unsigned short* __restrict__ HB,
                         unsigned short* __restrict__ GOUT, int colO, int selfCol, int n) {
  int gt = blockIdx.x*blockDim.x + threadIdx.x;
  int node = gt >> 5;
  int lane = gt & 31;
  if (node >= n) return;
  const uint2* gp = (const uint2*)GSRC;
  if (selfCol >= 0) {
    uint2 own = gp[(size_t)node*32 + lane];
    ((uint2*)HB)[(((size_t)node*HW + selfCol) >> 2) + lane] = own;
  }
  float a0 = 0.f, a1 = 0.f, a2 = 0.f, a3 = 0.f;
  int r0 = rowptr[node], r1 = rowptr[node+1];
  int e = r0;
  for (; e + 4 <= r1; e += 4) {
    int s0 = colI[e], s1 = colI[e+1], s2 = colI[e+2], s3 = colI[e+3];
    float w0 = wvv[e], w1 = wvv[e+1], w2 = wvv[e+2], w3 = wvv[e+3];
    uint2 u0 = gp[(size_t)s0*32 + lane];
    uint2 u1 = gp[(size_t)s1*32 + lane];
    uint2 u2 = gp[(size_t)s2*32 + lane];
    uint2 u3 = gp[(size_t)s3*32 + lane];
    a0 += w0*bf2f(u0.x & 0xffffu) + w1*bf2f(u1.x & 0xffffu)
        + w2*bf2f(u2.x & 0xffffu) + w3*bf2f(u3.x & 0xffffu);
    a1 += w0*bf2f(u0.x >> 16)     + w1*bf2f(u1.x >> 16)
        + w2*bf2f(u2.x >> 16)     + w3*bf2f(u3.x >> 16);
    a2 += w0*bf2f(u0.y & 0xffffu) + w1*bf2f(u1.y & 0xffffu)
        + w2*bf2f(u2.y & 0xffffu) + w3*bf2f(u3.y & 0xffffu);
    a3 += w0*bf2f(u0.y >> 16)     + w1*bf2f(u1.y >> 16)
        + w2*bf2f(u2.y >> 16)     + w3*bf2f(u3.y >> 16);
  }
  for (; e < r1; ++e) {
    int s = colI[e]; float w = wvv[e];
    uint2 u = gp[(size_t)s*32 + lane];
    a0 += w*bf2f(u.x & 0xffffu);
    a1 += w*bf2f(u.x >> 16);
    a2 += w*bf2f(u.y & 0xffffu);
    a3 += w*bf2f(u.y >> 16);
  }
  uint2 hw;
  hw.x = (unsigned int)f2bf(a0) | ((unsigned int)f2bf(a1) << 16);
  hw.y = (unsigned int)f2bf(a2) | ((unsigned int)f2bf(a3) << 16);
  ((uint2*)HB)[(((size_t)node*HW + colO) >> 2) + lane] = hw;
  if (GOUT) ((uint2*)GOUT)[(size_t)node*32 + lane] = hw;
}

// ---------------- fused MFMA GEMM + LSTM cell (r11 structure verbatim) ----
// 128 rows x 128 packed cols, 4 waves, ~27 KB LDS (5 blocks/CU = 20 waves).
// bf16x2 (A bf16, B hi/lo). Single-buffer 2-barrier staging — ALL structure
// variants lost: r10 dbuf (LDS 54K -> 2 blk/CU), r12 reg-prefetch (sched
// degenerated), r15 BM=256/512thr (VGPR-capped to 2 blk/CU, 16 waves).
// Bank-conflict-free: A rows 42 shorts (21 dwords), B planes 1026 (513 dw).
// A k-tiles: kt 0,1,2 from P0/P1/P2 (+t*32), kt 3..14 from HB ((kt-3)*32).
// XCD-chunked bijective swizzle. Epilogue writes h ONLY to HG (race-free).

__global__ __launch_bounds__(256) void k_gemm_lstm(
    const unsigned short* __restrict__ P0, const unsigned short* __restrict__ P1,
    const unsigned short* __restrict__ P2, const unsigned short* __restrict__ HB,
    const unsigned short* __restrict__ BH, const unsigned short* __restrict__ BL,
    const float* __restrict__ bsum, const float* __restrict__ wcp,
    float* __restrict__ Cst, float* __restrict__ Ht,
    unsigned short* __restrict__ HG,
    int N, int first, int ntk, int t) {
  union SMem {
    struct { unsigned short As[128][42]; unsigned short Bs[2][4][1026]; } g;
    float ep[32][132];
  };
  __shared__ SMem sm;
  const int tid = threadIdx.x;
  // XCD-chunked bijective remap (8 XCDs)
  int orig = blockIdx.y * gridDim.x + blockIdx.x;
  int nwg = gridDim.x * gridDim.y;
  int q8 = nwg >> 3, r8 = nwg & 7;
  int xcd = orig & 7, idx = orig >> 3;
  int newid = (xcd < r8 ? xcd*(q8+1) : r8*(q8+1) + (xcd-r8)*q8) + idx;
  const int bm = (newid >> 2) * 128;   // gridDim.x == 4
  const int bxi = newid & 3;
  const int bn = bxi * 128;
  const int bx32 = bxi * 32;
  const int lane = tid & 63;
  const int wid = tid >> 6;
  const int wr = wid >> 1;
  const int wcol = wid & 1;
  const int l15 = lane & 15;
  const int l4  = lane >> 4;
  const int tcol = t*32;
  f32x4 acc[4][4] = {};
  for (int kt = 0; kt < ntk; ++kt) {
    const unsigned short* Asrc; int coff;
    if (kt == 0)      { Asrc = P0; coff = tcol; }
    else if (kt == 1) { Asrc = P1; coff = tcol; }
    else if (kt == 2) { Asrc = P2; coff = tcol; }
    else              { Asrc = HB; coff = (kt-3)*32; }
    __syncthreads();
    #pragma unroll
    for (int r2 = 0; r2 < 2; ++r2) {
      int cc = tid + 256*r2;
      int row = cc >> 2, ko = (cc & 3) * 8;
      uint4 vh = make_uint4(0,0,0,0);
      if (bm + row < N) vh = *(const uint4*)(Asrc + (size_t)(bm + row)*384 + coff + ko);
      *(uint4*)&sm.g.As[row][ko] = vh;
      int kg = cc >> 7, col = cc & 127;
      size_t bo = ((size_t)((kt*4 + kg)*GDIM + bn + col))*8;
      *(uint4*)&sm.g.Bs[0][kg][col*8] = *(const uint4*)(BH + bo);
      *(uint4*)&sm.g.Bs[1][kg][col*8] = *(const uint4*)(BL + bo);
    }
    __syncthreads();
    bf16x8 ah[4];
    #pragma unroll
    for (int mi = 0; mi < 4; ++mi) {
      int r = wr*64 + mi*16 + l15;
      ah[mi] = *(const bf16x8*)&sm.g.As[r][l4*8];
    }
    #pragma unroll
    for (int ni = 0; ni < 4; ++ni) {
      int cidx = (wcol*64 + ni*16 + l15)*8;
      bf16x8 bh8 = *(const bf16x8*)&sm.g.Bs[0][l4][cidx];
      bf16x8 bl8 = *(const bf16x8*)&sm.g.Bs[1][l4][cidx];
      #pragma unroll
      for (int mi = 0; mi < 4; ++mi) {
        acc[mi][ni] = __builtin_amdgcn_mfma_f32_16x16x32_bf16(ah[mi], bh8, acc[mi][ni], 0,0,0);
        acc[mi][ni] = __builtin_amdgcn_mfma_f32_16x16x32_bf16(ah[mi], bl8, acc[mi][ni], 0,0,0);
      }
    }
  }
  // ---- epilogue: per mi, stage 32 rows x 128 packed cols, then LSTM ----
  for (int mi = 0; mi < 4; ++mi) {
    __syncthreads();
    #pragma unroll
    for (int ni = 0; ni < 4; ++ni)
      #pragma unroll
      for (int q = 0; q < 4; ++q)
        sm.ep[wr*16 + l4*4 + q][wcol*64 + ni*16 + l15] = acc[mi][ni][q];
    __syncthreads();
    #pragma unroll
    for (int r = 0; r < 4; ++r) {
      int item = tid + 256*r;            // 32 rows x 32 d
      int rloc = item >> 5, dd = item & 31;
      int row = bm + (rloc >> 4)*64 + mi*16 + (rloc & 15);
      if (row >= N) continue;
      int dg = bx32 + dd;
      f32x4 gv = *(f32x4*)&sm.ep[rloc][dd*4];   // i,f,c,o
      float c0 = first ? 0.0f : Cst[(size_t)row*D_HID + dg];
      float gi = gv[0] + bsum[dg]       + wcp[dg]*c0;
      float gf = gv[1] + bsum[128+dg]   + wcp[128+dg]*c0;
      float gc = gv[2] + bsum[256+dg];
      float go = gv[3] + bsum[384+dg];
      float ig = fsig(gi), fg = fsig(gf);
      float cn = fg*c0 + ig*ftanh(gc);
      float og = fsig(go + wcp[256+dg]*cn);
      float hn = og*ftanh(cn);
      Cst[(size_t)row*D_HID + dg] = cn;
      Ht[(size_t)row*D_HID + dg] = hn;
      HG[(size_t)row*D_HID + dg] = f2bf(hn);
    }
  }
}

// ---------------- final tanh + LayerNorm (in place on d_out) ----------------
// float4 per lane, 32 lanes per 128-elem row, 2 rows/wave (verified r13/r15).

__global__ __launch_bounds__(256) void k_ln(float* __restrict__ H, const float* __restrict__ gam,
                                            const float* __restrict__ bet, long rows) {
  long row = (long)blockIdx.x*8 + (threadIdx.x >> 5);
  int l32 = threadIdx.x & 31;
  if (row >= rows) return;
  float* p = H + row*(long)D_HID + l32*4;
  float4 v = *(float4*)p;
  float b0 = ftanh(v.x), b1 = ftanh(v.y), b2 = ftanh(v.z), b3 = ftanh(v.w);
  float s = b0 + b1 + b2 + b3;
  float q = b0*b0 + b1*b1 + b2*b2 + b3*b3;
  #pragma unroll
  for (int off = 16; off > 0; off >>= 1) {
    s += __shfl_xor(s, off);
    q += __shfl_xor(q, off);
  }
  float mu  = s * (1.0f/128.0f);
  float var = q * (1.0f/128.0f) - mu*mu;
  float rs  = rsqrtf(var + 1e-5f);
  float4 g = *(const float4*)(gam + l32*4);
  float4 be = *(const float4*)(bet + l32*4);
  float4 o;
  o.x = (b0 - mu)*rs*g.x + be.x;
  o.y = (b1 - mu)*rs*g.y + be.y;
  o.z = (b2 - mu)*rs*g.z + be.z;
  o.w = (b3 - mu)*rs*g.w + be.w;
  *(float4*)p = o;
}

// ---------------- launch ----------------

extern "C" void kernel_launch(void* const* d_in, const int* in_sizes, int n_in,
                              void* d_out, int out_size, void* d_ws, size_t ws_size,
                              hipStream_t stream) {
  const float* x   = (const float*)d_in[0];
  const int*   ei  = (const int*)  d_in[1];
  const float* Wx  = (const float*)d_in[2];
  const float* bx  = (const float*)d_in[3];
  const float* Wh  = (const float*)d_in[4];
  const float* bh  = (const float*)d_in[5];
  const float* wc  = (const float*)d_in[6];
  const float* bg  = (const float*)d_in[7];
  const float* lng = (const float*)d_in[8];
  const float* lnb = (const float*)d_in[9];
  const int N = in_sizes[0] / (C_IN*T_STEPS);
  const int E = in_sizes[1] / 2;
  const int* src = ei;
  const int* dst = ei + E;
  float* Hout = (float*)d_out;

  char* w = (char*)d_ws;
  auto alloc = [&](size_t bytes) -> char* {
    char* p = w; w += (bytes + 255) & ~size_t(255); return p;
  };
  unsigned short* P0 = (unsigned short*)alloc((size_t)N*XW*2);
  unsigned short* P1 = (unsigned short*)alloc((size_t)N*XW*2);
  unsigned short* P2 = (unsigned short*)alloc((size_t)N*XW*2);
  unsigned short* HB = (unsigned short*)alloc((size_t)N*HW*2);
  float* Cst   = (float*)alloc((size_t)N*D_HID*4);
  int*   aux   = (int*)  alloc((size_t)3*N*4);
  float* dis   = (float*)alloc((size_t)N*4);
  int*   rowptr= (int*)  alloc((size_t)(N+1)*4);
  int*   colI  = (int*)  alloc((size_t)E*4);
  float* wvv   = (float*)alloc((size_t)E*4);
  unsigned short* BH = (unsigned short*)alloc((size_t)KTOT*GDIM*2);
  unsigned short* BL = (unsigned short*)alloc((size_t)KTOT*GDIM*2);
  float* bsum  = (float*)alloc((size_t)GDIM*4);
  unsigned short* HG   = (unsigned short*)alloc((size_t)N*D_HID*2);
  unsigned short* Y1HG = (unsigned short*)alloc((size_t)N*D_HID*2);
  if ((size_t)(w - (char*)d_ws) > ws_size) return;

  int* cnt = aux; int* fil = aux + N; int* deg = aux + 2*N;

  k_zero_i<<<cdiv(3L*N,256),256,0,stream>>>(aux, 3*N);
  k_count<<<cdiv(E,256),256,0,stream>>>(src, dst, cnt, deg, E);
  k_dis<<<cdiv(N,256),256,0,stream>>>(deg, dis, N);
  k_scan<<<1,1024,0,stream>>>(cnt, rowptr, N);
  k_fill<<<cdiv(E,256),256,0,stream>>>(src, dst, rowptr, fil, dis, colI, wvv, E);
  k_packB<<<cdiv((long)KTOT*GDIM,256),256,0,stream>>>(Wx, Wh, BH, BL);
  k_bias<<<2,256,0,stream>>>(bx, bh, bg, bsum);

  // x-side for ALL timesteps: P0 = x, P1 = L@P0, P2 = L@P1  (3 dispatches)
  k_xt_all<<<cdiv((long)N*XW,256),256,0,stream>>>(x, P0, (long)N*XW);
  k_spmm_x<<<cdiv((long)N*96,256),256,0,stream>>>(rowptr, colI, wvv, P0, P1, N);
  k_spmm_x<<<cdiv((long)N*96,256),256,0,stream>>>(rowptr, colI, wvv, P1, P2, N);

  dim3 ggrid(GDIM/128, cdiv(N,128));
  for (int t = 0; t < T_STEPS; ++t) {
    // h-side basis: h copied to HB[0:128) by spmm #1; y1h -> [128,256); y2h -> [256,384)
    if (t > 0) {
      k_spmm_h<<<cdiv((long)N*32,256),256,0,stream>>>(rowptr, colI, wvv,
          HG, HB, Y1HG, 128, 0, N);
      k_spmm_h<<<cdiv((long)N*32,256),256,0,stream>>>(rowptr, colI, wvv,
          Y1HG, HB, nullptr, 256, -1, N);
    }
    // fused gates GEMM (bf16x2, gate-interleaved B) + LSTM epilogue
    int ntk = (t == 0) ? 3 : KTOT/32;   // t=0: h-cols zero, skip those k-tiles
    k_gemm_lstm<<<ggrid,256,0,stream>>>(P0, P1, P2, HB, BH, BL, bsum, wc,
        Cst, Hout + (size_t)t*N*D_HID, HG, N, t == 0 ? 1 : 0, ntk, t);
  }
  k_ln<<<cdiv((long)T_STEPS*N,8),256,0,stream>>>(Hout, lng, lnb, (long)T_STEPS*N);
}

// Round 17
// 2856.520 us; speedup vs baseline: 1.3451x; 1.1133x over previous
//
#include <hip/hip_runtime.h>
#include <math.h>

static constexpr int C_IN    = 32;
static constexpr int T_STEPS = 12;
static constexpr int D_HID   = 128;
static constexpr int KTOT    = 3*C_IN + 3*D_HID;  // 480
static constexpr int GDIM    = 4*D_HID;           // 512
static constexpr int XW      = T_STEPS*C_IN;      // 384: x-plane row width
static constexpr int HW      = 3*D_HID;           // 384: h-basis row width

static inline int cdiv(long a, int b) { return (int)((a + b - 1) / b); }

typedef __attribute__((ext_vector_type(8))) short bf16x8;
typedef __attribute__((ext_vector_type(4))) float f32x4;

__device__ __forceinline__ float bf2f(unsigned int u16) {
  union { unsigned int u; float f; } v; v.u = u16 << 16; return v.f;
}
__device__ __forceinline__ unsigned short f2bf(float f) {
  union { float f; unsigned int u; } v; v.f = f;
  unsigned int u = v.u + 0x7fffu + ((v.u >> 16) & 1u);  // RNE
  return (unsigned short)(u >> 16);
}
__device__ __forceinline__ float fsig(float x) { return 1.0f/(1.0f + __expf(-x)); }
__device__ __forceinline__ float ftanh(float x) {
  float e = __expf(2.0f*x);
  return 1.0f - 2.0f/(e + 1.0f);
}

// ---------------- CSR build ----------------

__global__ void k_zero_i(int* __restrict__ p, int n) {
  int i = blockIdx.x*blockDim.x + threadIdx.x;
  if (i < n) p[i] = 0;
}

__global__ void k_count(const int* __restrict__ src, const int* __restrict__ dst,
                        int* __restrict__ cnt, int* __restrict__ deg, int E) {
  int e = blockIdx.x*blockDim.x + threadIdx.x;
  if (e < E) {
    atomicAdd(&cnt[dst[e]], 1);
    atomicAdd(&deg[src[e]], 1);
  }
}

__global__ void k_dis(const int* __restrict__ deg, float* __restrict__ dis, int n) {
  int i = blockIdx.x*blockDim.x + threadIdx.x;
  if (i < n) {
    int d = deg[i];
    dis[i] = d > 0 ? rsqrtf((float)d) : 0.0f;
  }
}

__global__ __launch_bounds__(1024) void k_scan(const int* __restrict__ cnt,
                                               int* __restrict__ rowptr, int n) {
  __shared__ int wsum[16];
  __shared__ int carry_s;
  int tid = threadIdx.x; int lane = tid & 63; int wv_ = tid >> 6;
  if (tid == 0) { carry_s = 0; rowptr[0] = 0; }
  __syncthreads();
  for (int base = 0; base < n; base += 1024) {
    int i = base + tid;
    int s = (i < n) ? cnt[i] : 0;
    #pragma unroll
    for (int off = 1; off < 64; off <<= 1) {
      int t = __shfl_up(s, off);
      if (lane >= off) s += t;
    }
    if (lane == 63) wsum[wv_] = s;
    __syncthreads();
    if (tid < 16) {
      int ws = wsum[tid];
      #pragma unroll
      for (int off = 1; off < 16; off <<= 1) {
        int t = __shfl_up(ws, off);
        if (tid >= off) ws += t;
      }
      wsum[tid] = ws;
    }
    __syncthreads();
    int offw = carry_s + (wv_ > 0 ? wsum[wv_-1] : 0);
    if (i < n) rowptr[i+1] = offw + s;
    __syncthreads();
    if (tid == 0) carry_s = carry_s + wsum[15];
    __syncthreads();
  }
}

__global__ void k_fill(const int* __restrict__ src, const int* __restrict__ dst,
                       const int* __restrict__ rowptr, int* __restrict__ fil,
                       const float* __restrict__ dis,
                       int* __restrict__ colI, float* __restrict__ wvv, int E) {
  int e = blockIdx.x*blockDim.x + threadIdx.x;
  if (e < E) {
    int d = dst[e], s = src[e];
    int p = rowptr[d] + atomicAdd(&fil[d], 1);
    colI[p] = s;
    wvv[p] = -dis[s] * dis[d];
  }
}

// ---------------- weight packing ----------------
// Column permutation p = 4*d + g (gate-interleaved). Chebyshev refold:
// basis [v, y1=Lv, y2=L(Lv)] with weights [W0-W2, W1, 2*W2].
// k8-interleave: element (kk,p) at ((kt*4+kg)*512+p)*8+i, kk=kt*32+kg*8+i.
// Single bf16 plane (bf16x1): B-lo dropped for occupancy — weights sigma
// 0.05, bf16 rounding adds ~2e-3/step gate error, well inside threshold.

__global__ void k_packB(const float* __restrict__ Wx, const float* __restrict__ Wh,
                        unsigned short* __restrict__ BH) {
  int idx = blockIdx.x*blockDim.x + threadIdx.x;
  if (idx >= KTOT*GDIM) return;
  int kk = idx / GDIM, p = idx % GDIM;
  int g = p & 3, d = p >> 2;
  float v;
  if (kk < 96) {
    int k3 = kk >> 5, c = kk & 31;
    auto wx = [&](int k) { return Wx[((((size_t)g*3 + k)*32 + c) << 7) + d]; };
    v = (k3 == 0) ? wx(0) - wx(2) : (k3 == 1) ? wx(1) : 2.0f*wx(2);
  } else {
    int kk2 = kk - 96;
    int k3 = kk2 >> 7, j = kk2 & 127;
    auto wh = [&](int k) { return Wh[((((size_t)g*3 + k)*128 + j) << 7) + d]; };
    v = (k3 == 0) ? wh(0) - wh(2) : (k3 == 1) ? wh(1) : 2.0f*wh(2);
  }
  int kt = kk >> 5, kg = (kk >> 3) & 3, i = kk & 7;
  size_t o = ((size_t)((kt*4 + kg)*GDIM + p))*8 + i;
  BH[o] = f2bf(v);
}

__global__ void k_bias(const float* __restrict__ bx, const float* __restrict__ bh,
                       const float* __restrict__ bg, float* __restrict__ bsum) {
  int i = blockIdx.x*blockDim.x + threadIdx.x;
  if (i < GDIM) bsum[i] = bx[i] + bh[i] + bg[i];
}

// ---------------- staging ----------------

// P0[n][t*32+c] = bf16(x[n][c][t])  for all t at once
__global__ void k_xt_all(const float* __restrict__ x, unsigned short* __restrict__ P0,
                         long total) {
  long i = (long)blockIdx.x*blockDim.x + threadIdx.x;   // ((n*12+t)*32+c)
  if (i >= total) return;
  int c = (int)(i & 31);
  long nt = i >> 5;
  int t = (int)(nt % T_STEPS);
  long n = nt / T_STEPS;
  float v = x[(n*C_IN + c)*T_STEPS + t];
  P0[n*XW + t*C_IN + c] = f2bf(v);
}

// DST[n][0:384) = L_hat @ SRC   (compact planes, 96 uint2-lanes per node)
__global__ void k_spmm_x(const int* __restrict__ rowptr, const int* __restrict__ colI,
                         const float* __restrict__ wvv,
                         const unsigned short* __restrict__ SRC,
                         unsigned short* __restrict__ DST, int n) {
  int gt = blockIdx.x*blockDim.x + threadIdx.x;
  int node = gt / 96;
  int lane = gt - node*96;
  if (node >= n) return;
  const uint2* gp = (const uint2*)SRC;
  float a0 = 0.f, a1 = 0.f, a2 = 0.f, a3 = 0.f;
  int r0 = rowptr[node], r1 = rowptr[node+1];
  int e = r0;
  for (; e + 4 <= r1; e += 4) {
    int s0 = colI[e], s1 = colI[e+1], s2 = colI[e+2], s3 = colI[e+3];
    float w0 = wvv[e], w1 = wvv[e+1], w2 = wvv[e+2], w3 = wvv[e+3];
    uint2 u0 = gp[(size_t)s0*96 + lane];
    uint2 u1 = gp[(size_t)s1*96 + lane];
    uint2 u2 = gp[(size_t)s2*96 + lane];
    uint2 u3 = gp[(size_t)s3*96 + lane];
    a0 += w0*bf2f(u0.x & 0xffffu) + w1*bf2f(u1.x & 0xffffu)
        + w2*bf2f(u2.x & 0xffffu) + w3*bf2f(u3.x & 0xffffu);
    a1 += w0*bf2f(u0.x >> 16)     + w1*bf2f(u1.x >> 16)
        + w2*bf2f(u2.x >> 16)     + w3*bf2f(u3.x >> 16);
    a2 += w0*bf2f(u0.y & 0xffffu) + w1*bf2f(u1.y & 0xffffu)
        + w2*bf2f(u2.y & 0xffffu) + w3*bf2f(u3.y & 0xffffu);
    a3 += w0*bf2f(u0.y >> 16)     + w1*bf2f(u1.y >> 16)
        + w2*bf2f(u2.y >> 16)     + w3*bf2f(u3.y >> 16);
  }
  for (; e < r1; ++e) {
    int s = colI[e]; float w = wvv[e];
    uint2 u = gp[(size_t)s*96 + lane];
    a0 += w*bf2f(u.x & 0xffffu);
    a1 += w*bf2f(u.x >> 16);
    a2 += w*bf2f(u.y & 0xffffu);
    a3 += w*bf2f(u.y >> 16);
  }
  uint2 hw;
  hw.x = (unsigned int)f2bf(a0) | ((unsigned int)f2bf(a1) << 16);
  hw.y = (unsigned int)f2bf(a2) | ((unsigned int)f2bf(a3) << 16);
  ((uint2*)DST)[(size_t)node*96 + lane] = hw;
}

// h-side: y = L_hat @ GSRC (compact [n][128]); r11 structure verbatim —
// 32 lanes/node, uint2/lane, unroll-4 (best measured; r12/r13/r14 variants
// were neutral-to-worse: the gather sits at the cache-system ceiling).
__global__ void k_spmm_h(const int* __restrict__ rowptr, const int* __restrict__ colI,
                         const float* __restrict__ wvv,
                         const unsigned short* __restrict__ GSRC,
                         unsigned short* __restrict__ HB,
                         unsigned short* __restrict__ GOUT, int colO, int selfCol, int n) {
  int gt = blockIdx.x*blockDim.x + threadIdx.x;
  int node = gt >> 5;
  int lane = gt & 31;
  if (node >= n) return;
  const uint2* gp = (const uint2*)GSRC;
  if (selfCol >= 0) {
    uint2 own = gp[(size_t)node*32 + lane];
    ((uint2*)HB)[(((size_t)node*HW + selfCol) >> 2) + lane] = own;
  }
  float a0 = 0.f, a1 = 0.f, a2 = 0.f, a3 = 0.f;
  int r0 = rowptr[node], r1 = rowptr[node+1];
  int e = r0;
  for (; e + 4 <= r1; e += 4) {
    int s0 = colI[e], s1 = colI[e+1], s2 = colI[e+2], s3 = colI[e+3];
    float w0 = wvv[e], w1 = wvv[e+1], w2 = wvv[e+2], w3 = wvv[e+3];
    uint2 u0 = gp[(size_t)s0*32 + lane];
    uint2 u1 = gp[(size_t)s1*32 + lane];
    uint2 u2 = gp[(size_t)s2*32 + lane];
    uint2 u3 = gp[(size_t)s3*32 + lane];
    a0 += w0*bf2f(u0.x & 0xffffu) + w1*bf2f(u1.x & 0xffffu)
        + w2*bf2f(u2.x & 0xffffu) + w3*bf2f(u3.x & 0xffffu);
    a1 += w0*bf2f(u0.x >> 16)     + w1*bf2f(u1.x >> 16)
        + w2*bf2f(u2.x >> 16)     + w3*bf2f(u3.x >> 16);
    a2 += w0*bf2f(u0.y & 0xffffu) + w1*bf2f(u1.y & 0xffffu)
        + w2*bf2f(u2.y & 0xffffu) + w3*bf2f(u3.y & 0xffffu);
    a3 += w0*bf2f(u0.y >> 16)     + w1*bf2f(u1.y >> 16)
        + w2*bf2f(u2.y >> 16)     + w3*bf2f(u3.y >> 16);
  }
  for (; e < r1; ++e) {
    int s = colI[e]; float w = wvv[e];
    uint2 u = gp[(size_t)s*32 + lane];
    a0 += w*bf2f(u.x & 0xffffu);
    a1 += w*bf2f(u.x >> 16);
    a2 += w*bf2f(u.y & 0xffffu);
    a3 += w*bf2f(u.y >> 16);
  }
  uint2 hw;
  hw.x = (unsigned int)f2bf(a0) | ((unsigned int)f2bf(a1) << 16);
  hw.y = (unsigned int)f2bf(a2) | ((unsigned int)f2bf(a3) << 16);
  ((uint2*)HB)[(((size_t)node*HW + colO) >> 2) + lane] = hw;
  if (GOUT) ((uint2*)GOUT)[(size_t)node*32 + lane] = hw;
}

// ---------------- fused MFMA GEMM + LSTM cell ----------------
// r11 geometry, bf16x1 weights (B-lo dropped): LDS 27.2 -> 18.5 KB ->
// blocks/CU 5 -> 7 (72 VGPR cap) = 28 waves/CU. For this latency-bound
// kernel occupancy is the remaining lever (pipelining attempts r10/r12/r15
// all regressed). Staging loads/thread 6 -> 4 uint4; 16 MFMA/kt/wave.
// Bank-conflict-free: A rows 42 shorts (21 dwords), B plane 1026 (513 dw).
// A k-tiles: kt 0,1,2 from P0/P1/P2 (+t*32), kt 3..14 from HB ((kt-3)*32).
// XCD-chunked bijective swizzle. Epilogue writes h ONLY to HG (race-free).

__global__ __launch_bounds__(256) void k_gemm_lstm(
    const unsigned short* __restrict__ P0, const unsigned short* __restrict__ P1,
    const unsigned short* __restrict__ P2, const unsigned short* __restrict__ HB,
    const unsigned short* __restrict__ BH,
    const float* __restrict__ bsum, const float* __restrict__ wcp,
    float* __restrict__ Cst, float* __restrict__ Ht,
    unsigned short* __restrict__ HG,
    int N, int first, int ntk, int t) {
  union SMem {
    struct { unsigned short As[128][42]; unsigned short Bs[4][1026]; } g;
    float ep[32][132];
  };
  __shared__ SMem sm;
  const int tid = threadIdx.x;
  // XCD-chunked bijective remap (8 XCDs)
  int orig = blockIdx.y * gridDim.x + blockIdx.x;
  int nwg = gridDim.x * gridDim.y;
  int q8 = nwg >> 3, r8 = nwg & 7;
  int xcd = orig & 7, idx = orig >> 3;
  int newid = (xcd < r8 ? xcd*(q8+1) : r8*(q8+1) + (xcd-r8)*q8) + idx;
  const int bm = (newid >> 2) * 128;   // gridDim.x == 4
  const int bxi = newid & 3;
  const int bn = bxi * 128;
  const int bx32 = bxi * 32;
  const int lane = tid & 63;
  const int wid = tid >> 6;
  const int wr = wid >> 1;
  const int wcol = wid & 1;
  const int l15 = lane & 15;
  const int l4  = lane >> 4;
  const int tcol = t*32;
  f32x4 acc[4][4] = {};
  for (int kt = 0; kt < ntk; ++kt) {
    const unsigned short* Asrc; int coff;
    if (kt == 0)      { Asrc = P0; coff = tcol; }
    else if (kt == 1) { Asrc = P1; coff = tcol; }
    else if (kt == 2) { Asrc = P2; coff = tcol; }
    else              { Asrc = HB; coff = (kt-3)*32; }
    __syncthreads();
    #pragma unroll
    for (int r2 = 0; r2 < 2; ++r2) {
      int cc = tid + 256*r2;
      int row = cc >> 2, ko = (cc & 3) * 8;
      uint4 vh = make_uint4(0,0,0,0);
      if (bm + row < N) vh = *(const uint4*)(Asrc + (size_t)(bm + row)*384 + coff + ko);
      *(uint4*)&sm.g.As[row][ko] = vh;
      int kg = cc >> 7, col = cc & 127;
      size_t bo = ((size_t)((kt*4 + kg)*GDIM + bn + col))*8;
      *(uint4*)&sm.g.Bs[kg][col*8] = *(const uint4*)(BH + bo);
    }
    __syncthreads();
    bf16x8 ah[4];
    #pragma unroll
    for (int mi = 0; mi < 4; ++mi) {
      int r = wr*64 + mi*16 + l15;
      ah[mi] = *(const bf16x8*)&sm.g.As[r][l4*8];
    }
    #pragma unroll
    for (int ni = 0; ni < 4; ++ni) {
      int cidx = (wcol*64 + ni*16 + l15)*8;
      bf16x8 bh8 = *(const bf16x8*)&sm.g.Bs[l4][cidx];
      #pragma unroll
      for (int mi = 0; mi < 4; ++mi) {
        acc[mi][ni] = __builtin_amdgcn_mfma_f32_16x16x32_bf16(ah[mi], bh8, acc[mi][ni], 0,0,0);
      }
    }
  }
  // ---- epilogue: per mi, stage 32 rows x 128 packed cols, then LSTM ----
  for (int mi = 0; mi < 4; ++mi) {
    __syncthreads();
    #pragma unroll
    for (int ni = 0; ni < 4; ++ni)
      #pragma unroll
      for (int q = 0; q < 4; ++q)
        sm.ep[wr*16 + l4*4 + q][wcol*64 + ni*16 + l15] = acc[mi][ni][q];
    __syncthreads();
    #pragma unroll
    for (int r = 0; r < 4; ++r) {
      int item = tid + 256*r;            // 32 rows x 32 d
      int rloc = item >> 5, dd = item & 31;
      int row = bm + (rloc >> 4)*64 + mi*16 + (rloc & 15);
      if (row >= N) continue;
      int dg = bx32 + dd;
      f32x4 gv = *(f32x4*)&sm.ep[rloc][dd*4];   // i,f,c,o
      float c0 = first ? 0.0f : Cst[(size_t)row*D_HID + dg];
      float gi = gv[0] + bsum[dg]       + wcp[dg]*c0;
      float gf = gv[1] + bsum[128+dg]   + wcp[128+dg]*c0;
      float gc = gv[2] + bsum[256+dg];
      float go = gv[3] + bsum[384+dg];
      float ig = fsig(gi), fg = fsig(gf);
      float cn = fg*c0 + ig*ftanh(gc);
      float og = fsig(go + wcp[256+dg]*cn);
      float hn = og*ftanh(cn);
      Cst[(size_t)row*D_HID + dg] = cn;
      Ht[(size_t)row*D_HID + dg] = hn;
      HG[(size_t)row*D_HID + dg] = f2bf(hn);
    }
  }
}

// ---------------- final tanh + LayerNorm (in place on d_out) ----------------
// float4 per lane, 32 lanes per 128-elem row, 2 rows/wave (verified r13/r15).

__global__ __launch_bounds__(256) void k_ln(float* __restrict__ H, const float* __restrict__ gam,
                                            const float* __restrict__ bet, long rows) {
  long row = (long)blockIdx.x*8 + (threadIdx.x >> 5);
  int l32 = threadIdx.x & 31;
  if (row >= rows) return;
  float* p = H + row*(long)D_HID + l32*4;
  float4 v = *(float4*)p;
  float b0 = ftanh(v.x), b1 = ftanh(v.y), b2 = ftanh(v.z), b3 = ftanh(v.w);
  float s = b0 + b1 + b2 + b3;
  float q = b0*b0 + b1*b1 + b2*b2 + b3*b3;
  #pragma unroll
  for (int off = 16; off > 0; off >>= 1) {
    s += __shfl_xor(s, off);
    q += __shfl_xor(q, off);
  }
  float mu  = s * (1.0f/128.0f);
  float var = q * (1.0f/128.0f) - mu*mu;
  float rs  = rsqrtf(var + 1e-5f);
  float4 g = *(const float4*)(gam + l32*4);
  float4 be = *(const float4*)(bet + l32*4);
  float4 o;
  o.x = (b0 - mu)*rs*g.x + be.x;
  o.y = (b1 - mu)*rs*g.y + be.y;
  o.z = (b2 - mu)*rs*g.z + be.z;
  o.w = (b3 - mu)*rs*g.w + be.w;
  *(float4*)p = o;
}

// ---------------- launch ----------------

extern "C" void kernel_launch(void* const* d_in, const int* in_sizes, int n_in,
                              void* d_out, int out_size, void* d_ws, size_t ws_size,
                              hipStream_t stream) {
  const float* x   = (const float*)d_in[0];
  const int*   ei  = (const int*)  d_in[1];
  const float* Wx  = (const float*)d_in[2];
  const float* bx  = (const float*)d_in[3];
  const float* Wh  = (const float*)d_in[4];
  const float* bh  = (const float*)d_in[5];
  const float* wc  = (const float*)d_in[6];
  const float* bg  = (const float*)d_in[7];
  const float* lng = (const float*)d_in[8];
  const float* lnb = (const float*)d_in[9];
  const int N = in_sizes[0] / (C_IN*T_STEPS);
  const int E = in_sizes[1] / 2;
  const int* src = ei;
  const int* dst = ei + E;
  float* Hout = (float*)d_out;

  char* w = (char*)d_ws;
  auto alloc = [&](size_t bytes) -> char* {
    char* p = w; w += (bytes + 255) & ~size_t(255); return p;
  };
  unsigned short* P0 = (unsigned short*)alloc((size_t)N*XW*2);
  unsigned short* P1 = (unsigned short*)alloc((size_t)N*XW*2);
  unsigned short* P2 = (unsigned short*)alloc((size_t)N*XW*2);
  unsigned short* HB = (unsigned short*)alloc((size_t)N*HW*2);
  float* Cst   = (float*)alloc((size_t)N*D_HID*4);
  int*   aux   = (int*)  alloc((size_t)3*N*4);
  float* dis   = (float*)alloc((size_t)N*4);
  int*   rowptr= (int*)  alloc((size_t)(N+1)*4);
  int*   colI  = (int*)  alloc((size_t)E*4);
  float* wvv   = (float*)alloc((size_t)E*4);
  unsigned short* BH = (unsigned short*)alloc((size_t)KTOT*GDIM*2);
  float* bsum  = (float*)alloc((size_t)GDIM*4);
  unsigned short* HG   = (unsigned short*)alloc((size_t)N*D_HID*2);
  unsigned short* Y1HG = (unsigned short*)alloc((size_t)N*D_HID*2);
  if ((size_t)(w - (char*)d_ws) > ws_size) return;

  int* cnt = aux; int* fil = aux + N; int* deg = aux + 2*N;

  k_zero_i<<<cdiv(3L*N,256),256,0,stream>>>(aux, 3*N);
  k_count<<<cdiv(E,256),256,0,stream>>>(src, dst, cnt, deg, E);
  k_dis<<<cdiv(N,256),256,0,stream>>>(deg, dis, N);
  k_scan<<<1,1024,0,stream>>>(cnt, rowptr, N);
  k_fill<<<cdiv(E,256),256,0,stream>>>(src, dst, rowptr, fil, dis, colI, wvv, E);
  k_packB<<<cdiv((long)KTOT*GDIM,256),256,0,stream>>>(Wx, Wh, BH);
  k_bias<<<2,256,0,stream>>>(bx, bh, bg, bsum);

  // x-side for ALL timesteps: P0 = x, P1 = L@P0, P2 = L@P1  (3 dispatches)
  k_xt_all<<<cdiv((long)N*XW,256),256,0,stream>>>(x, P0, (long)N*XW);
  k_spmm_x<<<cdiv((long)N*96,256),256,0,stream>>>(rowptr, colI, wvv, P0, P1, N);
  k_spmm_x<<<cdiv((long)N*96,256),256,0,stream>>>(rowptr, colI, wvv, P1, P2, N);

  dim3 ggrid(GDIM/128, cdiv(N,128));
  for (int t = 0; t < T_STEPS; ++t) {
    // h-side basis: h copied to HB[0:128) by spmm #1; y1h -> [128,256); y2h -> [256,384)
    if (t > 0) {
      k_spmm_h<<<cdiv((long)N*32,256),256,0,stream>>>(rowptr, colI, wvv,
          HG, HB, Y1HG, 128, 0, N);
      k_spmm_h<<<cdiv((long)N*32,256),256,0,stream>>>(rowptr, colI, wvv,
          Y1HG, HB, nullptr, 256, -1, N);
    }
    // fused gates GEMM (bf16x1, gate-interleaved B) + LSTM epilogue
    int ntk = (t == 0) ? 3 : KTOT/32;   // t=0: h-cols zero, skip those k-tiles
    k_gemm_lstm<<<ggrid,256,0,stream>>>(P0, P1, P2, HB, BH, bsum, wc,
        Cst, Hout + (size_t)t*N*D_HID, HG, N, t == 0 ? 1 : 0, ntk, t);
  }
  k_ln<<<cdiv((long)T_STEPS*N,8),256,0,stream>>>(Hout, lng, lnb, (long)T_STEPS*N);
}